// Round 11
// baseline (1466.102 us; speedup 1.0000x reference)
//
#include <hip/hip_runtime.h>

#define SEQ    2048
#define BATCH  2
#define DMODEL 1024
#define NHEAD  16
#define DH     64
#define MROWS  (SEQ*BATCH)        // 4096
#define RS     (BATCH*DMODEL)     // 2048
#define LN_EPS 1e-12f

// ---- bf16 bit helpers (intermediates only; in/out are fp32) ----
__device__ __forceinline__ float bf2f(unsigned short s) {
    union { unsigned u; float f; } a; a.u = ((unsigned)s) << 16; return a.f;
}
__device__ __forceinline__ unsigned short f2bf(float x) {
    union { float f; unsigned u; } a; a.f = x;
    unsigned r = a.u + 0x7fffu + ((a.u >> 16) & 1u);
    return (unsigned short)(r >> 16);
}

// beacon for structural failure (ws too small) — fp32 this time
__global__ void beacon_kernel(float* out, float val) {
    if (threadIdx.x == 0) out[0] = val;
}

// ---------------------------------------------------------------
// Pure-VALU fp32 GEMM: C[m][n] = sum_k A[m][k]*W[n][k] + bias[n]
// A fp32 MxK, W fp32 NxK (nn.Linear weight). 64x64 tile, BK=16,
// 256 threads, 4x4 per thread. Output bf16.
// ---------------------------------------------------------------
__global__ __launch_bounds__(256)
void qkv_valu(const float* __restrict__ q_in, const float* __restrict__ k_in,
              const float* __restrict__ v_in,
              const float* __restrict__ Wq, const float* __restrict__ bq,
              const float* __restrict__ Wk, const float* __restrict__ bk,
              const float* __restrict__ Wv, const float* __restrict__ bv,
              unsigned short* __restrict__ Qo, unsigned short* __restrict__ Ko,
              unsigned short* __restrict__ Vo)
{
    const float *A, *W, *B; unsigned short* C;
    if (blockIdx.z == 0)      { A = q_in; W = Wq; B = bq; C = Qo; }
    else if (blockIdx.z == 1) { A = k_in; W = Wk; B = bk; C = Ko; }
    else                      { A = v_in; W = Wv; B = bv; C = Vo; }

    __shared__ float As[16][65];   // [k][m]
    __shared__ float Bs[16][65];   // [k][n]

    const int tid = threadIdx.x;
    const int tx = tid & 15;
    const int ty = tid >> 4;
    const int m0 = blockIdx.x * 64;
    const int n0 = blockIdx.y * 64;

    float acc[4][4];
    #pragma unroll
    for (int i = 0; i < 4; ++i)
        #pragma unroll
        for (int j = 0; j < 4; ++j) acc[i][j] = 0.f;

    for (int k0 = 0; k0 < DMODEL; k0 += 16) {
        #pragma unroll
        for (int i = 0; i < 4; ++i) {
            int flat = tid + i * 256;
            int r = flat >> 4;
            int c = flat & 15;
            As[c][r] = A[(m0 + r) * DMODEL + k0 + c];
            Bs[c][r] = W[(n0 + r) * DMODEL + k0 + c];
        }
        __syncthreads();
        #pragma unroll
        for (int k = 0; k < 16; ++k) {
            float a0 = As[k][ty*4+0], a1 = As[k][ty*4+1],
                  a2 = As[k][ty*4+2], a3 = As[k][ty*4+3];
            float b0 = Bs[k][tx*4+0], b1 = Bs[k][tx*4+1],
                  b2 = Bs[k][tx*4+2], b3 = Bs[k][tx*4+3];
            acc[0][0] += a0*b0; acc[0][1] += a0*b1; acc[0][2] += a0*b2; acc[0][3] += a0*b3;
            acc[1][0] += a1*b0; acc[1][1] += a1*b1; acc[1][2] += a1*b2; acc[1][3] += a1*b3;
            acc[2][0] += a2*b0; acc[2][1] += a2*b1; acc[2][2] += a2*b2; acc[2][3] += a2*b3;
            acc[3][0] += a3*b0; acc[3][1] += a3*b1; acc[3][2] += a3*b2; acc[3][3] += a3*b3;
        }
        __syncthreads();
    }

    #pragma unroll
    for (int i = 0; i < 4; ++i) {
        int m = m0 + ty*4 + i;
        #pragma unroll
        for (int j = 0; j < 4; ++j) {
            int n = n0 + tx*4 + j;
            C[m * DMODEL + n] = f2bf(acc[i][j] + B[n]);
        }
    }
}

// o-proj: A is our bf16 context, W fp32; output fp32.
__global__ __launch_bounds__(256)
void oproj_valu(const unsigned short* __restrict__ Cx,
                const float* __restrict__ Wo, const float* __restrict__ bo,
                float* __restrict__ O32)
{
    __shared__ float As[16][65];
    __shared__ float Bs[16][65];
    const int tid = threadIdx.x;
    const int tx = tid & 15;
    const int ty = tid >> 4;
    const int m0 = blockIdx.x * 64;
    const int n0 = blockIdx.y * 64;

    float acc[4][4];
    #pragma unroll
    for (int i = 0; i < 4; ++i)
        #pragma unroll
        for (int j = 0; j < 4; ++j) acc[i][j] = 0.f;

    for (int k0 = 0; k0 < DMODEL; k0 += 16) {
        #pragma unroll
        for (int i = 0; i < 4; ++i) {
            int flat = tid + i * 256;
            int r = flat >> 4;
            int c = flat & 15;
            As[c][r] = bf2f(Cx[(m0 + r) * DMODEL + k0 + c]);
            Bs[c][r] = Wo[(n0 + r) * DMODEL + k0 + c];
        }
        __syncthreads();
        #pragma unroll
        for (int k = 0; k < 16; ++k) {
            float a0 = As[k][ty*4+0], a1 = As[k][ty*4+1],
                  a2 = As[k][ty*4+2], a3 = As[k][ty*4+3];
            float b0 = Bs[k][tx*4+0], b1 = Bs[k][tx*4+1],
                  b2 = Bs[k][tx*4+2], b3 = Bs[k][tx*4+3];
            acc[0][0] += a0*b0; acc[0][1] += a0*b1; acc[0][2] += a0*b2; acc[0][3] += a0*b3;
            acc[1][0] += a1*b0; acc[1][1] += a1*b1; acc[1][2] += a1*b2; acc[1][3] += a1*b3;
            acc[2][0] += a2*b0; acc[2][1] += a2*b1; acc[2][2] += a2*b2; acc[2][3] += a2*b3;
            acc[3][0] += a3*b0; acc[3][1] += a3*b1; acc[3][2] += a3*b2; acc[3][3] += a3*b3;
        }
        __syncthreads();
    }

    #pragma unroll
    for (int i = 0; i < 4; ++i) {
        int m = m0 + ty*4 + i;
        #pragma unroll
        for (int j = 0; j < 4; ++j) {
            int n = n0 + tx*4 + j;
            O32[m * DMODEL + n] = acc[i][j] + bo[n];
        }
    }
}

// ---------------------------------------------------------------
// fp32 VALU flash attention. Block = 64 q-rows x 1 head-batch.
// Q read from and Ctx written to the same buffer (disjoint per block).
// NOTE: reference applies NO 1/sqrt(dh) scaling.
// ---------------------------------------------------------------
__global__ __launch_bounds__(256)
void attn_valu(const unsigned short* __restrict__ Q,
               const unsigned short* __restrict__ Kg,
               const unsigned short* __restrict__ V,
               unsigned short* __restrict__ Ctx)
{
    __shared__ __align__(16) float Qs[64*65];
    __shared__ __align__(16) float Kt[64*68];
    __shared__ __align__(16) float Vs[64*68];
    __shared__ __align__(16) float Ps[64*68];

    const int tid = threadIdx.x;
    const int qr  = tid >> 2;
    const int c0  = (tid & 3) * 16;
    const int q0  = blockIdx.x * 64;
    const int bh  = blockIdx.y;
    const int off = (bh >> 4) * DMODEL + (bh & 15) * DH;

    #pragma unroll
    for (int i = 0; i < 2; ++i) {
        int idx = tid + i * 256;
        int r = idx >> 3, c8 = (idx & 7) * 8;
        union { uint4 u; unsigned short s[8]; } uw;
        uw.u = *(const uint4*)&Q[(q0 + r) * RS + off + c8];
        #pragma unroll
        for (int j = 0; j < 8; ++j) Qs[r*65 + c8 + j] = bf2f(uw.s[j]);
    }

    float m = -1e30f, l = 0.f;
    float O[16];
    #pragma unroll
    for (int a = 0; a < 16; ++a) O[a] = 0.f;

    for (int kt = 0; kt < SEQ/64; ++kt) {
        __syncthreads();
        const int kb = kt * 64;
        #pragma unroll
        for (int i = 0; i < 2; ++i) {
            int idx = tid + i * 256;
            int r = idx >> 3, c8 = (idx & 7) * 8;
            union { uint4 u; unsigned short s[8]; } kw, vw;
            kw.u = *(const uint4*)&Kg[(kb + r) * RS + off + c8];
            vw.u = *(const uint4*)&V [(kb + r) * RS + off + c8];
            #pragma unroll
            for (int j = 0; j < 8; ++j) {
                Kt[(c8 + j)*68 + r] = bf2f(kw.s[j]);
                Vs[r*68 + c8 + j]   = bf2f(vw.s[j]);
            }
        }
        __syncthreads();

        float s[16];
        #pragma unroll
        for (int a = 0; a < 16; ++a) s[a] = 0.f;
        for (int d = 0; d < 64; ++d) {
            float qv = Qs[qr*65 + d];
            float4 k0v = *(const float4*)&Kt[d*68 + c0];
            float4 k1v = *(const float4*)&Kt[d*68 + c0 + 4];
            float4 k2v = *(const float4*)&Kt[d*68 + c0 + 8];
            float4 k3v = *(const float4*)&Kt[d*68 + c0 + 12];
            s[0]  += qv * k0v.x; s[1]  += qv * k0v.y; s[2]  += qv * k0v.z; s[3]  += qv * k0v.w;
            s[4]  += qv * k1v.x; s[5]  += qv * k1v.y; s[6]  += qv * k1v.z; s[7]  += qv * k1v.w;
            s[8]  += qv * k2v.x; s[9]  += qv * k2v.y; s[10] += qv * k2v.z; s[11] += qv * k2v.w;
            s[12] += qv * k3v.x; s[13] += qv * k3v.y; s[14] += qv * k3v.z; s[15] += qv * k3v.w;
        }

        float mx = s[0];
        #pragma unroll
        for (int a = 1; a < 16; ++a) mx = fmaxf(mx, s[a]);
        mx = fmaxf(mx, __shfl_xor(mx, 1));
        mx = fmaxf(mx, __shfl_xor(mx, 2));
        float mnew = fmaxf(m, mx);
        float alpha = __expf(m - mnew);
        float psum = 0.f;
        #pragma unroll
        for (int a = 0; a < 16; ++a) {
            float p = __expf(s[a] - mnew);
            Ps[qr*68 + c0 + a] = p;
            psum += p;
        }
        psum += __shfl_xor(psum, 1);
        psum += __shfl_xor(psum, 2);
        l = l * alpha + psum;
        m = mnew;
        #pragma unroll
        for (int a = 0; a < 16; ++a) O[a] *= alpha;

        __syncthreads();

        for (int kk = 0; kk < 64; ++kk) {
            float pv = Ps[qr*68 + kk];
            float4 v0 = *(const float4*)&Vs[kk*68 + c0];
            float4 v1 = *(const float4*)&Vs[kk*68 + c0 + 4];
            float4 v2 = *(const float4*)&Vs[kk*68 + c0 + 8];
            float4 v3 = *(const float4*)&Vs[kk*68 + c0 + 12];
            O[0]  += pv * v0.x; O[1]  += pv * v0.y; O[2]  += pv * v0.z; O[3]  += pv * v0.w;
            O[4]  += pv * v1.x; O[5]  += pv * v1.y; O[6]  += pv * v1.z; O[7]  += pv * v1.w;
            O[8]  += pv * v2.x; O[9]  += pv * v2.y; O[10] += pv * v2.z; O[11] += pv * v2.w;
            O[12] += pv * v3.x; O[13] += pv * v3.y; O[14] += pv * v3.z; O[15] += pv * v3.w;
        }
    }

    float inv = 1.f / l;
    #pragma unroll
    for (int a = 0; a < 16; ++a)
        Ctx[(q0 + qr) * RS + off + c0 + a] = f2bf(O[a] * inv);
}

// ---------------------------------------------------------------
// LayerNorm(out + residual): fp32 in, FP32 OUT (the round-10 fix).
// ---------------------------------------------------------------
__global__ __launch_bounds__(256)
void ln2_kernel(const float* __restrict__ O,
                const float* __restrict__ resid,
                const float* __restrict__ w,
                const float* __restrict__ bb,
                float* __restrict__ out)
{
    __shared__ float r1[256];
    __shared__ float r2[256];
    const int row = blockIdx.x;
    const int tid = threadIdx.x;
    const int c4 = tid * 4;

    float4 o4 = *(const float4*)&O[row * DMODEL + c4];
    float4 q4 = *(const float4*)&resid[row * DMODEL + c4];
    float x0 = o4.x + q4.x;
    float x1 = o4.y + q4.y;
    float x2 = o4.z + q4.z;
    float x3 = o4.w + q4.w;

    r1[tid] = x0 + x1 + x2 + x3;
    r2[tid] = x0*x0 + x1*x1 + x2*x2 + x3*x3;
    __syncthreads();
    for (int st = 128; st > 0; st >>= 1) {
        if (tid < st) { r1[tid] += r1[tid + st]; r2[tid] += r2[tid + st]; }
        __syncthreads();
    }
    const float mean = r1[0] * (1.f / DMODEL);
    float var = r2[0] * (1.f / DMODEL) - mean * mean;
    var = fmaxf(var, 0.f);
    const float rstd = rsqrtf(var + LN_EPS);

    float4 w4 = *(const float4*)&w[c4];
    float4 b4 = *(const float4*)&bb[c4];
    float4 y;
    y.x = w4.x * ((x0 - mean) * rstd) + b4.x;
    y.y = w4.y * ((x1 - mean) * rstd) + b4.y;
    y.z = w4.z * ((x2 - mean) * rstd) + b4.z;
    y.w = w4.w * ((x3 - mean) * rstd) + b4.w;
    *(float4*)&out[row * DMODEL + c4] = y;
}

// ---------------------------------------------------------------
extern "C" void kernel_launch(void* const* d_in, const int* in_sizes, int n_in,
                              void* d_out, int out_size, void* d_ws, size_t ws_size,
                              hipStream_t stream) {
    // Inputs fp32, dict order (size-signature verified round 5).
    const float* q_in = (const float*)d_in[0];
    const float* k_in = (const float*)d_in[1];
    const float* v_in = (const float*)d_in[2];
    const float* Wq = (const float*)d_in[3];  const float* bq = (const float*)d_in[4];
    const float* Wk = (const float*)d_in[5];  const float* bk = (const float*)d_in[6];
    const float* Wv = (const float*)d_in[7];  const float* bv = (const float*)d_in[8];
    const float* Wo = (const float*)d_in[9];  const float* bo = (const float*)d_in[10];
    const float* lnw = (const float*)d_in[11]; const float* lnb = (const float*)d_in[12];

    // ws (>=16MB, verified rounds 5-9): Kb,Vb bf16; O32 fp32 overlays after attn.
    // Q/Ctx bf16 live in d_out's first 8MB (d_out is 16MB fp32), dead before
    // the final fp32 LN write.
    char* wsb = (char*)d_ws;
    unsigned short* Kb  = (unsigned short*)(wsb);
    unsigned short* Vb  = (unsigned short*)(wsb + (8u << 20));
    float*          O32 = (float*)(wsb);
    unsigned short* QCtx = (unsigned short*)d_out;
    float*          outF = (float*)d_out;

    const bool ws_ok = ws_size >= (16u << 20);

    dim3 blk(256);
    if (ws_ok) {
        qkv_valu<<<dim3(MROWS/64, DMODEL/64, 3), blk, 0, stream>>>(
            q_in, k_in, v_in, Wq, bq, Wk, bk, Wv, bv, QCtx, Kb, Vb);
        attn_valu<<<dim3(SEQ/64, BATCH*NHEAD), blk, 0, stream>>>(QCtx, Kb, Vb, QCtx);
        oproj_valu<<<dim3(MROWS/64, DMODEL/64), blk, 0, stream>>>(QCtx, Wo, bo, O32);
        ln2_kernel<<<dim3(MROWS), blk, 0, stream>>>(O32, q_in, lnw, lnb, outF);
    } else {
        beacon_kernel<<<1, 64, 0, stream>>>((float*)d_out, 300.0f);
    }
}

// Round 12
// 387.444 us; speedup vs baseline: 3.7840x; 3.7840x over previous
//
#include <hip/hip_runtime.h>

#define SEQ    2048
#define BATCH  2
#define DMODEL 1024
#define NHEAD  16
#define DH     64
#define MROWS  (SEQ*BATCH)        // 4096
#define RS     (BATCH*DMODEL)     // 2048
#define LN_EPS 1e-12f

typedef __attribute__((ext_vector_type(8))) short short8;
typedef __attribute__((ext_vector_type(4))) float floatx4;

// ---- bf16 bit helpers (intermediates only; in/out are fp32) ----
__device__ __forceinline__ float bf2f(unsigned short s) {
    union { unsigned u; float f; } a; a.u = ((unsigned)s) << 16; return a.f;
}
__device__ __forceinline__ unsigned short f2bf(float x) {
    union { float f; unsigned u; } a; a.f = x;
    unsigned r = a.u + 0x7fffu + ((a.u >> 16) & 1u);
    return (unsigned short)(r >> 16);
}
// 8 contiguous fp32 -> 8 bf16 packed in uint4
__device__ __forceinline__ uint4 cvt8(const float* __restrict__ p) {
    float4 x0 = *(const float4*)(p);
    float4 x1 = *(const float4*)(p + 4);
    union { uint4 u; unsigned short s[8]; } r;
    r.s[0] = f2bf(x0.x); r.s[1] = f2bf(x0.y);
    r.s[2] = f2bf(x0.z); r.s[3] = f2bf(x0.w);
    r.s[4] = f2bf(x1.x); r.s[5] = f2bf(x1.y);
    r.s[6] = f2bf(x1.z); r.s[7] = f2bf(x1.w);
    return r.u;
}

__global__ void beacon_kernel(float* out, float val) {
    if (threadIdx.x == 0) out[0] = val;
}

// ---------------------------------------------------------------
// MFMA GEMM: C[m][n] = sum_k A[m][k]*W[n][k] + bias[n]
// A fp32 MxK, W fp32 NxK. 128x128 tile, BK=32, 4 waves (64x64 each,
// 4x4 MFMAs of 16x16x32). Output bf16.
// ---------------------------------------------------------------
__global__ __launch_bounds__(256)
void qkv_mfma(const float* __restrict__ q_in, const float* __restrict__ k_in,
              const float* __restrict__ v_in,
              const float* __restrict__ Wq, const float* __restrict__ bq,
              const float* __restrict__ Wk, const float* __restrict__ bk,
              const float* __restrict__ Wv, const float* __restrict__ bv,
              unsigned short* __restrict__ Qo, unsigned short* __restrict__ Ko,
              unsigned short* __restrict__ Vo)
{
    const float *A, *W, *B; unsigned short* C;
    if (blockIdx.z == 0)      { A = q_in; W = Wq; B = bq; C = Qo; }
    else if (blockIdx.z == 1) { A = k_in; W = Wk; B = bk; C = Ko; }
    else                      { A = v_in; W = Wv; B = bv; C = Vo; }

    __shared__ __align__(16) short Alds[128*32];
    __shared__ __align__(16) short Blds[128*32];

    const int tid  = threadIdx.x;
    const int lane = tid & 63;
    const int wave = tid >> 6;
    const int lrow = lane & 15;
    const int lq   = lane >> 4;
    const int m0 = blockIdx.x * 128;
    const int n0 = blockIdx.y * 128;
    const int mw = (wave >> 1) * 64;
    const int nw = (wave & 1) * 64;
    const int K  = DMODEL;

    floatx4 zero = {0.f, 0.f, 0.f, 0.f};
    floatx4 acc[4][4];
    #pragma unroll
    for (int i = 0; i < 4; ++i)
        #pragma unroll
        for (int j = 0; j < 4; ++j) acc[i][j] = zero;

    for (int k0 = 0; k0 < K; k0 += 32) {
        #pragma unroll
        for (int rep = 0; rep < 2; ++rep) {
            int chunk = tid + rep * 256;           // 0..511
            int row = chunk >> 2;                   // 128 rows
            int col = (chunk & 3) << 3;             // 0,8,16,24
            *(uint4*)&Alds[row*32 + col] = cvt8(&A[(m0 + row) * K + k0 + col]);
            *(uint4*)&Blds[row*32 + col] = cvt8(&W[(n0 + row) * K + k0 + col]);
        }
        __syncthreads();
        short8 af[4], bfg[4];
        #pragma unroll
        for (int mi = 0; mi < 4; ++mi)
            af[mi] = *(const short8*)&Alds[(mw + mi*16 + lrow)*32 + lq*8];
        #pragma unroll
        for (int ni = 0; ni < 4; ++ni)
            bfg[ni] = *(const short8*)&Blds[(nw + ni*16 + lrow)*32 + lq*8];
        #pragma unroll
        for (int mi = 0; mi < 4; ++mi)
            #pragma unroll
            for (int ni = 0; ni < 4; ++ni)
                acc[mi][ni] = __builtin_amdgcn_mfma_f32_16x16x32_bf16(af[mi], bfg[ni], acc[mi][ni], 0, 0, 0);
        __syncthreads();
    }

    #pragma unroll
    for (int mi = 0; mi < 4; ++mi) {
        #pragma unroll
        for (int ni = 0; ni < 4; ++ni) {
            int n = n0 + nw + ni*16 + lrow;
            float bv_ = B[n];
            #pragma unroll
            for (int r = 0; r < 4; ++r) {
                int m = m0 + mw + mi*16 + lq*4 + r;
                C[m * DMODEL + n] = f2bf(acc[mi][ni][r] + bv_);
            }
        }
    }
}

// o-proj: A = bf16 context, W fp32; output fp32.
__global__ __launch_bounds__(256)
void oproj_mfma(const unsigned short* __restrict__ Cx,
                const float* __restrict__ Wo, const float* __restrict__ bo,
                float* __restrict__ O32)
{
    __shared__ __align__(16) short Alds[128*32];
    __shared__ __align__(16) short Blds[128*32];

    const int tid  = threadIdx.x;
    const int lane = tid & 63;
    const int wave = tid >> 6;
    const int lrow = lane & 15;
    const int lq   = lane >> 4;
    const int m0 = blockIdx.x * 128;
    const int n0 = blockIdx.y * 128;
    const int mw = (wave >> 1) * 64;
    const int nw = (wave & 1) * 64;
    const int K  = DMODEL;

    floatx4 zero = {0.f, 0.f, 0.f, 0.f};
    floatx4 acc[4][4];
    #pragma unroll
    for (int i = 0; i < 4; ++i)
        #pragma unroll
        for (int j = 0; j < 4; ++j) acc[i][j] = zero;

    for (int k0 = 0; k0 < K; k0 += 32) {
        #pragma unroll
        for (int rep = 0; rep < 2; ++rep) {
            int chunk = tid + rep * 256;
            int row = chunk >> 2;
            int col = (chunk & 3) << 3;
            *(uint4*)&Alds[row*32 + col] = *(const uint4*)&Cx[(m0 + row) * K + k0 + col];
            *(uint4*)&Blds[row*32 + col] = cvt8(&Wo[(n0 + row) * K + k0 + col]);
        }
        __syncthreads();
        short8 af[4], bfg[4];
        #pragma unroll
        for (int mi = 0; mi < 4; ++mi)
            af[mi] = *(const short8*)&Alds[(mw + mi*16 + lrow)*32 + lq*8];
        #pragma unroll
        for (int ni = 0; ni < 4; ++ni)
            bfg[ni] = *(const short8*)&Blds[(nw + ni*16 + lrow)*32 + lq*8];
        #pragma unroll
        for (int mi = 0; mi < 4; ++mi)
            #pragma unroll
            for (int ni = 0; ni < 4; ++ni)
                acc[mi][ni] = __builtin_amdgcn_mfma_f32_16x16x32_bf16(af[mi], bfg[ni], acc[mi][ni], 0, 0, 0);
        __syncthreads();
    }

    #pragma unroll
    for (int mi = 0; mi < 4; ++mi) {
        #pragma unroll
        for (int ni = 0; ni < 4; ++ni) {
            int n = n0 + nw + ni*16 + lrow;
            float bv_ = bo[n];
            #pragma unroll
            for (int r = 0; r < 4; ++r) {
                int m = m0 + mw + mi*16 + lq*4 + r;
                O32[m * DMODEL + n] = acc[mi][ni][r] + bv_;
            }
        }
    }
}

// ---------------------------------------------------------------
// MFMA flash attention. Block = 64 q-rows x 1 head-batch, 4 waves.
// Q/Ctx in the same buffer (disjoint per-block read-then-write).
// NOTE: reference applies NO 1/sqrt(dh) scaling.
// ---------------------------------------------------------------
__global__ __launch_bounds__(256)
void attn_mfma(const unsigned short* __restrict__ Q,
               const unsigned short* __restrict__ Kg,
               const unsigned short* __restrict__ V,
               unsigned short* __restrict__ Ctx)
{
    __shared__ __align__(16) short Qs[64*72];
    __shared__ __align__(16) short Ks[64*72];
    __shared__ __align__(16) short Vt[64*72];     // Vt[d][kk^swz]
    __shared__ __align__(16) short Ps[4][16*72];  // per-wave P strip

    const int tid  = threadIdx.x;
    const int lane = tid & 63;
    const int wave = tid >> 6;
    const int lrow = lane & 15;
    const int lq   = lane >> 4;

    const int q0 = blockIdx.x * 64;
    const int bh = blockIdx.y;
    const int off = (bh >> 4) * DMODEL + (bh & 15) * DH;

    // stage Q tile
    #pragma unroll
    for (int rep = 0; rep < 2; ++rep) {
        int chunk = tid + rep * 256;
        int r = chunk >> 3;
        int c = (chunk & 7) << 3;
        *(uint4*)&Qs[r*72 + c] = *(const uint4*)&Q[(q0 + r) * RS + off + c];
    }

    floatx4 zero = {0.f, 0.f, 0.f, 0.f};
    float m_i[4], l_i[4];
    floatx4 oacc[4];
    #pragma unroll
    for (int r = 0; r < 4; ++r) { m_i[r] = -1e30f; l_i[r] = 0.f; }
    #pragma unroll
    for (int ni = 0; ni < 4; ++ni) oacc[ni] = zero;

    for (int kt = 0; kt < SEQ/64; ++kt) {
        __syncthreads();               // prior readers done / Qs visible
        const int kbase = kt * 64;
        #pragma unroll
        for (int rep = 0; rep < 2; ++rep) {
            int chunk = tid + rep * 256;
            int r = chunk >> 3;            // kk within tile
            int c = (chunk & 7) << 3;      // d chunk
            *(uint4*)&Ks[r*72 + c] = *(const uint4*)&Kg[(kbase + r) * RS + off + c];
            uint4 vv = *(const uint4*)&V[(kbase + r) * RS + off + c];
            union { uint4 u; short s[8]; } uv; uv.u = vv;
            int swz = (chunk & 7) << 3;    // == ((c+j)>>3)<<3
            #pragma unroll
            for (int j = 0; j < 8; ++j)
                Vt[(c + j)*72 + (r ^ swz)] = uv.s[j];
        }
        __syncthreads();

        // ---- S = Q Ktile^T ----
        short8 aq[2];
        #pragma unroll
        for (int ks = 0; ks < 2; ++ks)
            aq[ks] = *(const short8*)&Qs[(wave*16 + lrow)*72 + ks*32 + lq*8];
        floatx4 sacc[4];
        #pragma unroll
        for (int ni = 0; ni < 4; ++ni) sacc[ni] = zero;
        #pragma unroll
        for (int ni = 0; ni < 4; ++ni) {
            #pragma unroll
            for (int ks = 0; ks < 2; ++ks) {
                short8 kf = *(const short8*)&Ks[(ni*16 + lrow)*72 + ks*32 + lq*8];
                sacc[ni] = __builtin_amdgcn_mfma_f32_16x16x32_bf16(aq[ks], kf, sacc[ni], 0, 0, 0);
            }
        }

        // ---- online softmax (row r ↔ q = wave*16+lq*4+r; cols across 16 lanes) ----
        float alpha[4], p[4][4];
        #pragma unroll
        for (int r = 0; r < 4; ++r) {
            float v = fmaxf(fmaxf(sacc[0][r], sacc[1][r]), fmaxf(sacc[2][r], sacc[3][r]));
            v = fmaxf(v, __shfl_xor(v, 1));
            v = fmaxf(v, __shfl_xor(v, 2));
            v = fmaxf(v, __shfl_xor(v, 4));
            v = fmaxf(v, __shfl_xor(v, 8));
            float mnew = fmaxf(m_i[r], v);
            alpha[r] = __expf(m_i[r] - mnew);
            m_i[r] = mnew;
        }
        #pragma unroll
        for (int ni = 0; ni < 4; ++ni)
            #pragma unroll
            for (int r = 0; r < 4; ++r)
                p[ni][r] = __expf(sacc[ni][r] - m_i[r]);
        #pragma unroll
        for (int r = 0; r < 4; ++r) {
            float sv = p[0][r] + p[1][r] + p[2][r] + p[3][r];
            sv += __shfl_xor(sv, 1);
            sv += __shfl_xor(sv, 2);
            sv += __shfl_xor(sv, 4);
            sv += __shfl_xor(sv, 8);
            l_i[r] = l_i[r] * alpha[r] + sv;
        }
        #pragma unroll
        for (int ni = 0; ni < 4; ++ni)
            #pragma unroll
            for (int r = 0; r < 4; ++r)
                oacc[ni][r] *= alpha[r];

        // ---- P: C-layout regs -> LDS -> A-operand layout ----
        #pragma unroll
        for (int ni = 0; ni < 4; ++ni)
            #pragma unroll
            for (int r = 0; r < 4; ++r)
                Ps[wave][(lq*4 + r)*72 + ni*16 + lrow] = (short)f2bf(p[ni][r]);

        __syncthreads();   // also keeps Ks/Vt stable until all waves done

        short8 ap[2];
        #pragma unroll
        for (int ks = 0; ks < 2; ++ks)
            ap[ks] = *(const short8*)&Ps[wave][lrow*72 + ks*32 + lq*8];
        #pragma unroll
        for (int ni = 0; ni < 4; ++ni) {
            #pragma unroll
            for (int ks = 0; ks < 2; ++ks) {
                int d  = ni*16 + lrow;
                int kk = ks*32 + lq*8;
                int swz = ((d >> 3) & 7) << 3;
                short8 vf = *(const short8*)&Vt[d*72 + (kk ^ swz)];
                oacc[ni] = __builtin_amdgcn_mfma_f32_16x16x32_bf16(ap[ks], vf, oacc[ni], 0, 0, 0);
            }
        }
    }

    #pragma unroll
    for (int r = 0; r < 4; ++r) l_i[r] = 1.f / l_i[r];
    #pragma unroll
    for (int ni = 0; ni < 4; ++ni) {
        #pragma unroll
        for (int r = 0; r < 4; ++r) {
            int q = q0 + wave*16 + lq*4 + r;
            int d = ni*16 + lrow;
            Ctx[q * RS + off + d] = f2bf(oacc[ni][r] * l_i[r]);
        }
    }
}

// ---------------------------------------------------------------
// LayerNorm(out + residual): fp32 in, fp32 out.
// ---------------------------------------------------------------
__global__ __launch_bounds__(256)
void ln2_kernel(const float* __restrict__ O,
                const float* __restrict__ resid,
                const float* __restrict__ w,
                const float* __restrict__ bb,
                float* __restrict__ out)
{
    __shared__ float r1[256];
    __shared__ float r2[256];
    const int row = blockIdx.x;
    const int tid = threadIdx.x;
    const int c4 = tid * 4;

    float4 o4 = *(const float4*)&O[row * DMODEL + c4];
    float4 q4 = *(const float4*)&resid[row * DMODEL + c4];
    float x0 = o4.x + q4.x;
    float x1 = o4.y + q4.y;
    float x2 = o4.z + q4.z;
    float x3 = o4.w + q4.w;

    r1[tid] = x0 + x1 + x2 + x3;
    r2[tid] = x0*x0 + x1*x1 + x2*x2 + x3*x3;
    __syncthreads();
    for (int st = 128; st > 0; st >>= 1) {
        if (tid < st) { r1[tid] += r1[tid + st]; r2[tid] += r2[tid + st]; }
        __syncthreads();
    }
    const float mean = r1[0] * (1.f / DMODEL);
    float var = r2[0] * (1.f / DMODEL) - mean * mean;
    var = fmaxf(var, 0.f);
    const float rstd = rsqrtf(var + LN_EPS);

    float4 w4 = *(const float4*)&w[c4];
    float4 b4 = *(const float4*)&bb[c4];
    float4 y;
    y.x = w4.x * ((x0 - mean) * rstd) + b4.x;
    y.y = w4.y * ((x1 - mean) * rstd) + b4.y;
    y.z = w4.z * ((x2 - mean) * rstd) + b4.z;
    y.w = w4.w * ((x3 - mean) * rstd) + b4.w;
    *(float4*)&out[row * DMODEL + c4] = y;
}

// ---------------------------------------------------------------
extern "C" void kernel_launch(void* const* d_in, const int* in_sizes, int n_in,
                              void* d_out, int out_size, void* d_ws, size_t ws_size,
                              hipStream_t stream) {
    const float* q_in = (const float*)d_in[0];
    const float* k_in = (const float*)d_in[1];
    const float* v_in = (const float*)d_in[2];
    const float* Wq = (const float*)d_in[3];  const float* bq = (const float*)d_in[4];
    const float* Wk = (const float*)d_in[5];  const float* bk = (const float*)d_in[6];
    const float* Wv = (const float*)d_in[7];  const float* bv = (const float*)d_in[8];
    const float* Wo = (const float*)d_in[9];  const float* bo = (const float*)d_in[10];
    const float* lnw = (const float*)d_in[11]; const float* lnb = (const float*)d_in[12];

    // ws >=16MB (verified): Kb,Vb bf16; O32 fp32 overlays after attention.
    // Q/Ctx bf16 live in d_out's first 8MB, dead before the fp32 LN write.
    char* wsb = (char*)d_ws;
    unsigned short* Kb  = (unsigned short*)(wsb);
    unsigned short* Vb  = (unsigned short*)(wsb + (8u << 20));
    float*          O32 = (float*)(wsb);
    unsigned short* QCtx = (unsigned short*)d_out;
    float*          outF = (float*)d_out;

    const bool ws_ok = ws_size >= (16u << 20);

    dim3 blk(256);
    if (ws_ok) {
        qkv_mfma<<<dim3(MROWS/128, DMODEL/128, 3), blk, 0, stream>>>(
            q_in, k_in, v_in, Wq, bq, Wk, bk, Wv, bv, QCtx, Kb, Vb);
        attn_mfma<<<dim3(SEQ/64, BATCH*NHEAD), blk, 0, stream>>>(QCtx, Kb, Vb, QCtx);
        oproj_mfma<<<dim3(MROWS/128, DMODEL/128), blk, 0, stream>>>(QCtx, Wo, bo, O32);
        ln2_kernel<<<dim3(MROWS), blk, 0, stream>>>(O32, q_in, lnw, lnb, outF);
    } else {
        beacon_kernel<<<1, 64, 0, stream>>>((float*)d_out, 300.0f);
    }
}

// Round 13
// 343.504 us; speedup vs baseline: 4.2681x; 1.1279x over previous
//
#include <hip/hip_runtime.h>

#define SEQ    2048
#define BATCH  2
#define DMODEL 1024
#define NHEAD  16
#define DH     64
#define MROWS  (SEQ*BATCH)        // 4096
#define RS     (BATCH*DMODEL)     // 2048
#define LN_EPS 1e-12f

typedef __attribute__((ext_vector_type(8))) short short8;
typedef __attribute__((ext_vector_type(4))) float floatx4;

// ---- bf16 bit helpers (intermediates only; in/out are fp32) ----
__device__ __forceinline__ float bf2f(unsigned short s) {
    union { unsigned u; float f; } a; a.u = ((unsigned)s) << 16; return a.f;
}
__device__ __forceinline__ unsigned short f2bf(float x) {
    union { float f; unsigned u; } a; a.f = x;
    unsigned r = a.u + 0x7fffu + ((a.u >> 16) & 1u);
    return (unsigned short)(r >> 16);
}
__device__ __forceinline__ uint4 cvt8(const float* __restrict__ p) {
    float4 x0 = *(const float4*)(p);
    float4 x1 = *(const float4*)(p + 4);
    union { uint4 u; unsigned short s[8]; } r;
    r.s[0] = f2bf(x0.x); r.s[1] = f2bf(x0.y);
    r.s[2] = f2bf(x0.z); r.s[3] = f2bf(x0.w);
    r.s[4] = f2bf(x1.x); r.s[5] = f2bf(x1.y);
    r.s[6] = f2bf(x1.z); r.s[7] = f2bf(x1.w);
    return r.u;
}

__global__ void beacon_kernel(float* out, float val) {
    if (threadIdx.x == 0) out[0] = val;
}

// ---------------------------------------------------------------
// One-shot fp32 -> bf16 conversion of inputs + weights.
// z in [0,7): 0..2 = q,k,v (4M elems); 3..6 = Wq,Wk,Wv,Wo (1M elems).
// ---------------------------------------------------------------
__global__ __launch_bounds__(256)
void cvt_kernel(const float* __restrict__ s0, const float* __restrict__ s1,
                const float* __restrict__ s2, const float* __restrict__ s3,
                const float* __restrict__ s4, const float* __restrict__ s5,
                const float* __restrict__ s6,
                unsigned short* __restrict__ d0, unsigned short* __restrict__ d1,
                unsigned short* __restrict__ d2, unsigned short* __restrict__ d3,
                unsigned short* __restrict__ d4, unsigned short* __restrict__ d5,
                unsigned short* __restrict__ d6)
{
    const float* srcs[7] = {s0, s1, s2, s3, s4, s5, s6};
    unsigned short* dsts[7] = {d0, d1, d2, d3, d4, d5, d6};
    const int cnts[7] = {4194304, 4194304, 4194304, 1048576, 1048576, 1048576, 1048576};
    const int z = blockIdx.z;
    const float* src = srcs[z];
    unsigned short* dst = dsts[z];
    const int count = cnts[z];
    const int stride = gridDim.x * 256 * 8;
    for (int i = (blockIdx.x * 256 + threadIdx.x) * 8; i < count; i += stride)
        *(uint4*)&dst[i] = cvt8(&src[i]);
}

// ---------------------------------------------------------------
// bf16 MFMA GEMM: C[m][n] = sum_k A[m][k]*W[n][k] + bias[n]
// A,W bf16 row-major (W = N x K). 128x128 tile, BK=32, 4 waves.
// ---------------------------------------------------------------
template<int OUTF32>
__device__ __forceinline__ void gemm_bf16_body(
    const unsigned short* __restrict__ A,
    const unsigned short* __restrict__ W,
    const float* __restrict__ bias,
    void* __restrict__ Cout)
{
    __shared__ __align__(16) short Alds[128*32];
    __shared__ __align__(16) short Blds[128*32];

    const int tid  = threadIdx.x;
    const int lane = tid & 63;
    const int wave = tid >> 6;
    const int lrow = lane & 15;
    const int lq   = lane >> 4;
    const int m0 = blockIdx.x * 128;
    const int n0 = blockIdx.y * 128;
    const int mw = (wave >> 1) * 64;
    const int nw = (wave & 1) * 64;
    const int K  = DMODEL;

    floatx4 zero = {0.f, 0.f, 0.f, 0.f};
    floatx4 acc[4][4];
    #pragma unroll
    for (int i = 0; i < 4; ++i)
        #pragma unroll
        for (int j = 0; j < 4; ++j) acc[i][j] = zero;

    for (int k0 = 0; k0 < K; k0 += 32) {
        #pragma unroll
        for (int rep = 0; rep < 2; ++rep) {
            int chunk = tid + rep * 256;
            int row = chunk >> 2;
            int col = (chunk & 3) << 3;
            *(uint4*)&Alds[row*32 + col] = *(const uint4*)&A[(m0 + row) * K + k0 + col];
            *(uint4*)&Blds[row*32 + col] = *(const uint4*)&W[(n0 + row) * K + k0 + col];
        }
        __syncthreads();
        short8 af[4], bfg[4];
        #pragma unroll
        for (int mi = 0; mi < 4; ++mi)
            af[mi] = *(const short8*)&Alds[(mw + mi*16 + lrow)*32 + lq*8];
        #pragma unroll
        for (int ni = 0; ni < 4; ++ni)
            bfg[ni] = *(const short8*)&Blds[(nw + ni*16 + lrow)*32 + lq*8];
        #pragma unroll
        for (int mi = 0; mi < 4; ++mi)
            #pragma unroll
            for (int ni = 0; ni < 4; ++ni)
                acc[mi][ni] = __builtin_amdgcn_mfma_f32_16x16x32_bf16(af[mi], bfg[ni], acc[mi][ni], 0, 0, 0);
        __syncthreads();
    }

    #pragma unroll
    for (int mi = 0; mi < 4; ++mi) {
        #pragma unroll
        for (int ni = 0; ni < 4; ++ni) {
            int n = n0 + nw + ni*16 + lrow;
            float bv_ = bias[n];
            #pragma unroll
            for (int r = 0; r < 4; ++r) {
                int m = m0 + mw + mi*16 + lq*4 + r;
                float v = acc[mi][ni][r] + bv_;
                if (OUTF32) ((float*)Cout)[m * DMODEL + n] = v;
                else ((unsigned short*)Cout)[m * DMODEL + n] = f2bf(v);
            }
        }
    }
}

__global__ __launch_bounds__(256)
void qkv_bf16(const unsigned short* __restrict__ qb, const unsigned short* __restrict__ kb,
              const unsigned short* __restrict__ vb,
              const unsigned short* __restrict__ Wqb, const float* __restrict__ bq,
              const unsigned short* __restrict__ Wkb, const float* __restrict__ bk,
              const unsigned short* __restrict__ Wvb, const float* __restrict__ bv,
              unsigned short* __restrict__ Qo, unsigned short* __restrict__ Ko,
              unsigned short* __restrict__ Vo)
{
    const unsigned short *A, *W; const float* B; unsigned short* C;
    if (blockIdx.z == 0)      { A = qb; W = Wqb; B = bq; C = Qo; }
    else if (blockIdx.z == 1) { A = kb; W = Wkb; B = bk; C = Ko; }
    else                      { A = vb; W = Wvb; B = bv; C = Vo; }
    gemm_bf16_body<0>(A, W, B, C);
}

__global__ __launch_bounds__(256)
void oproj_bf16(const unsigned short* __restrict__ Cx,
                const unsigned short* __restrict__ Wob, const float* __restrict__ bo,
                float* __restrict__ O32)
{
    gemm_bf16_body<1>(Cx, Wob, bo, O32);
}

// ---------------- fallback (round-12, fused-cvt) GEMMs ----------------
__global__ __launch_bounds__(256)
void qkv_mfma(const float* __restrict__ q_in, const float* __restrict__ k_in,
              const float* __restrict__ v_in,
              const float* __restrict__ Wq, const float* __restrict__ bq,
              const float* __restrict__ Wk, const float* __restrict__ bk,
              const float* __restrict__ Wv, const float* __restrict__ bv,
              unsigned short* __restrict__ Qo, unsigned short* __restrict__ Ko,
              unsigned short* __restrict__ Vo)
{
    const float *A, *W, *B; unsigned short* C;
    if (blockIdx.z == 0)      { A = q_in; W = Wq; B = bq; C = Qo; }
    else if (blockIdx.z == 1) { A = k_in; W = Wk; B = bk; C = Ko; }
    else                      { A = v_in; W = Wv; B = bv; C = Vo; }

    __shared__ __align__(16) short Alds[128*32];
    __shared__ __align__(16) short Blds[128*32];
    const int tid  = threadIdx.x;
    const int lane = tid & 63;
    const int wave = tid >> 6;
    const int lrow = lane & 15;
    const int lq   = lane >> 4;
    const int m0 = blockIdx.x * 128;
    const int n0 = blockIdx.y * 128;
    const int mw = (wave >> 1) * 64;
    const int nw = (wave & 1) * 64;
    const int K  = DMODEL;

    floatx4 zero = {0.f, 0.f, 0.f, 0.f};
    floatx4 acc[4][4];
    #pragma unroll
    for (int i = 0; i < 4; ++i)
        #pragma unroll
        for (int j = 0; j < 4; ++j) acc[i][j] = zero;

    for (int k0 = 0; k0 < K; k0 += 32) {
        #pragma unroll
        for (int rep = 0; rep < 2; ++rep) {
            int chunk = tid + rep * 256;
            int row = chunk >> 2;
            int col = (chunk & 3) << 3;
            *(uint4*)&Alds[row*32 + col] = cvt8(&A[(m0 + row) * K + k0 + col]);
            *(uint4*)&Blds[row*32 + col] = cvt8(&W[(n0 + row) * K + k0 + col]);
        }
        __syncthreads();
        short8 af[4], bfg[4];
        #pragma unroll
        for (int mi = 0; mi < 4; ++mi)
            af[mi] = *(const short8*)&Alds[(mw + mi*16 + lrow)*32 + lq*8];
        #pragma unroll
        for (int ni = 0; ni < 4; ++ni)
            bfg[ni] = *(const short8*)&Blds[(nw + ni*16 + lrow)*32 + lq*8];
        #pragma unroll
        for (int mi = 0; mi < 4; ++mi)
            #pragma unroll
            for (int ni = 0; ni < 4; ++ni)
                acc[mi][ni] = __builtin_amdgcn_mfma_f32_16x16x32_bf16(af[mi], bfg[ni], acc[mi][ni], 0, 0, 0);
        __syncthreads();
    }

    #pragma unroll
    for (int mi = 0; mi < 4; ++mi) {
        #pragma unroll
        for (int ni = 0; ni < 4; ++ni) {
            int n = n0 + nw + ni*16 + lrow;
            float bv_ = B[n];
            #pragma unroll
            for (int r = 0; r < 4; ++r) {
                int m = m0 + mw + mi*16 + lq*4 + r;
                C[m * DMODEL + n] = f2bf(acc[mi][ni][r] + bv_);
            }
        }
    }
}

__global__ __launch_bounds__(256)
void oproj_mfma(const unsigned short* __restrict__ Cx,
                const float* __restrict__ Wo, const float* __restrict__ bo,
                float* __restrict__ O32)
{
    __shared__ __align__(16) short Alds[128*32];
    __shared__ __align__(16) short Blds[128*32];
    const int tid  = threadIdx.x;
    const int lane = tid & 63;
    const int wave = tid >> 6;
    const int lrow = lane & 15;
    const int lq   = lane >> 4;
    const int m0 = blockIdx.x * 128;
    const int n0 = blockIdx.y * 128;
    const int mw = (wave >> 1) * 64;
    const int nw = (wave & 1) * 64;
    const int K  = DMODEL;

    floatx4 zero = {0.f, 0.f, 0.f, 0.f};
    floatx4 acc[4][4];
    #pragma unroll
    for (int i = 0; i < 4; ++i)
        #pragma unroll
        for (int j = 0; j < 4; ++j) acc[i][j] = zero;

    for (int k0 = 0; k0 < K; k0 += 32) {
        #pragma unroll
        for (int rep = 0; rep < 2; ++rep) {
            int chunk = tid + rep * 256;
            int row = chunk >> 2;
            int col = (chunk & 3) << 3;
            *(uint4*)&Alds[row*32 + col] = *(const uint4*)&Cx[(m0 + row) * K + k0 + col];
            *(uint4*)&Blds[row*32 + col] = cvt8(&Wo[(n0 + row) * K + k0 + col]);
        }
        __syncthreads();
        short8 af[4], bfg[4];
        #pragma unroll
        for (int mi = 0; mi < 4; ++mi)
            af[mi] = *(const short8*)&Alds[(mw + mi*16 + lrow)*32 + lq*8];
        #pragma unroll
        for (int ni = 0; ni < 4; ++ni)
            bfg[ni] = *(const short8*)&Blds[(nw + ni*16 + lrow)*32 + lq*8];
        #pragma unroll
        for (int mi = 0; mi < 4; ++mi)
            #pragma unroll
            for (int ni = 0; ni < 4; ++ni)
                acc[mi][ni] = __builtin_amdgcn_mfma_f32_16x16x32_bf16(af[mi], bfg[ni], acc[mi][ni], 0, 0, 0);
        __syncthreads();
    }

    #pragma unroll
    for (int mi = 0; mi < 4; ++mi) {
        #pragma unroll
        for (int ni = 0; ni < 4; ++ni) {
            int n = n0 + nw + ni*16 + lrow;
            float bv_ = bo[n];
            #pragma unroll
            for (int r = 0; r < 4; ++r) {
                int m = m0 + mw + mi*16 + lq*4 + r;
                O32[m * DMODEL + n] = acc[mi][ni][r] + bv_;
            }
        }
    }
}

// ---------------------------------------------------------------
// MFMA flash attention (unchanged from round 12).
// ---------------------------------------------------------------
__global__ __launch_bounds__(256)
void attn_mfma(const unsigned short* __restrict__ Q,
               const unsigned short* __restrict__ Kg,
               const unsigned short* __restrict__ V,
               unsigned short* __restrict__ Ctx)
{
    __shared__ __align__(16) short Qs[64*72];
    __shared__ __align__(16) short Ks[64*72];
    __shared__ __align__(16) short Vt[64*72];
    __shared__ __align__(16) short Ps[4][16*72];

    const int tid  = threadIdx.x;
    const int lane = tid & 63;
    const int wave = tid >> 6;
    const int lrow = lane & 15;
    const int lq   = lane >> 4;

    const int q0 = blockIdx.x * 64;
    const int bh = blockIdx.y;
    const int off = (bh >> 4) * DMODEL + (bh & 15) * DH;

    #pragma unroll
    for (int rep = 0; rep < 2; ++rep) {
        int chunk = tid + rep * 256;
        int r = chunk >> 3;
        int c = (chunk & 7) << 3;
        *(uint4*)&Qs[r*72 + c] = *(const uint4*)&Q[(q0 + r) * RS + off + c];
    }

    floatx4 zero = {0.f, 0.f, 0.f, 0.f};
    float m_i[4], l_i[4];
    floatx4 oacc[4];
    #pragma unroll
    for (int r = 0; r < 4; ++r) { m_i[r] = -1e30f; l_i[r] = 0.f; }
    #pragma unroll
    for (int ni = 0; ni < 4; ++ni) oacc[ni] = zero;

    for (int kt = 0; kt < SEQ/64; ++kt) {
        __syncthreads();
        const int kbase = kt * 64;
        #pragma unroll
        for (int rep = 0; rep < 2; ++rep) {
            int chunk = tid + rep * 256;
            int r = chunk >> 3;
            int c = (chunk & 7) << 3;
            *(uint4*)&Ks[r*72 + c] = *(const uint4*)&Kg[(kbase + r) * RS + off + c];
            uint4 vv = *(const uint4*)&V[(kbase + r) * RS + off + c];
            union { uint4 u; short s[8]; } uv; uv.u = vv;
            int swz = (chunk & 7) << 3;
            #pragma unroll
            for (int j = 0; j < 8; ++j)
                Vt[(c + j)*72 + (r ^ swz)] = uv.s[j];
        }
        __syncthreads();

        short8 aq[2];
        #pragma unroll
        for (int ks = 0; ks < 2; ++ks)
            aq[ks] = *(const short8*)&Qs[(wave*16 + lrow)*72 + ks*32 + lq*8];
        floatx4 sacc[4];
        #pragma unroll
        for (int ni = 0; ni < 4; ++ni) sacc[ni] = zero;
        #pragma unroll
        for (int ni = 0; ni < 4; ++ni) {
            #pragma unroll
            for (int ks = 0; ks < 2; ++ks) {
                short8 kf = *(const short8*)&Ks[(ni*16 + lrow)*72 + ks*32 + lq*8];
                sacc[ni] = __builtin_amdgcn_mfma_f32_16x16x32_bf16(aq[ks], kf, sacc[ni], 0, 0, 0);
            }
        }

        float alpha[4], p[4][4];
        #pragma unroll
        for (int r = 0; r < 4; ++r) {
            float v = fmaxf(fmaxf(sacc[0][r], sacc[1][r]), fmaxf(sacc[2][r], sacc[3][r]));
            v = fmaxf(v, __shfl_xor(v, 1));
            v = fmaxf(v, __shfl_xor(v, 2));
            v = fmaxf(v, __shfl_xor(v, 4));
            v = fmaxf(v, __shfl_xor(v, 8));
            float mnew = fmaxf(m_i[r], v);
            alpha[r] = __expf(m_i[r] - mnew);
            m_i[r] = mnew;
        }
        #pragma unroll
        for (int ni = 0; ni < 4; ++ni)
            #pragma unroll
            for (int r = 0; r < 4; ++r)
                p[ni][r] = __expf(sacc[ni][r] - m_i[r]);
        #pragma unroll
        for (int r = 0; r < 4; ++r) {
            float sv = p[0][r] + p[1][r] + p[2][r] + p[3][r];
            sv += __shfl_xor(sv, 1);
            sv += __shfl_xor(sv, 2);
            sv += __shfl_xor(sv, 4);
            sv += __shfl_xor(sv, 8);
            l_i[r] = l_i[r] * alpha[r] + sv;
        }
        #pragma unroll
        for (int ni = 0; ni < 4; ++ni)
            #pragma unroll
            for (int r = 0; r < 4; ++r)
                oacc[ni][r] *= alpha[r];

        #pragma unroll
        for (int ni = 0; ni < 4; ++ni)
            #pragma unroll
            for (int r = 0; r < 4; ++r)
                Ps[wave][(lq*4 + r)*72 + ni*16 + lrow] = (short)f2bf(p[ni][r]);

        __syncthreads();

        short8 ap[2];
        #pragma unroll
        for (int ks = 0; ks < 2; ++ks)
            ap[ks] = *(const short8*)&Ps[wave][lrow*72 + ks*32 + lq*8];
        #pragma unroll
        for (int ni = 0; ni < 4; ++ni) {
            #pragma unroll
            for (int ks = 0; ks < 2; ++ks) {
                int d  = ni*16 + lrow;
                int kk = ks*32 + lq*8;
                int swz = ((d >> 3) & 7) << 3;
                short8 vf = *(const short8*)&Vt[d*72 + (kk ^ swz)];
                oacc[ni] = __builtin_amdgcn_mfma_f32_16x16x32_bf16(ap[ks], vf, oacc[ni], 0, 0, 0);
            }
        }
    }

    #pragma unroll
    for (int r = 0; r < 4; ++r) l_i[r] = 1.f / l_i[r];
    #pragma unroll
    for (int ni = 0; ni < 4; ++ni) {
        #pragma unroll
        for (int r = 0; r < 4; ++r) {
            int q = q0 + wave*16 + lq*4 + r;
            int d = ni*16 + lrow;
            Ctx[q * RS + off + d] = f2bf(oacc[ni][r] * l_i[r]);
        }
    }
}

// ---------------------------------------------------------------
// LayerNorm(out + residual): fp32 in, fp32 out.
// ---------------------------------------------------------------
__global__ __launch_bounds__(256)
void ln2_kernel(const float* __restrict__ O,
                const float* __restrict__ resid,
                const float* __restrict__ w,
                const float* __restrict__ bb,
                float* __restrict__ out)
{
    __shared__ float r1[256];
    __shared__ float r2[256];
    const int row = blockIdx.x;
    const int tid = threadIdx.x;
    const int c4 = tid * 4;

    float4 o4 = *(const float4*)&O[row * DMODEL + c4];
    float4 q4 = *(const float4*)&resid[row * DMODEL + c4];
    float x0 = o4.x + q4.x;
    float x1 = o4.y + q4.y;
    float x2 = o4.z + q4.z;
    float x3 = o4.w + q4.w;

    r1[tid] = x0 + x1 + x2 + x3;
    r2[tid] = x0*x0 + x1*x1 + x2*x2 + x3*x3;
    __syncthreads();
    for (int st = 128; st > 0; st >>= 1) {
        if (tid < st) { r1[tid] += r1[tid + st]; r2[tid] += r2[tid + st]; }
        __syncthreads();
    }
    const float mean = r1[0] * (1.f / DMODEL);
    float var = r2[0] * (1.f / DMODEL) - mean * mean;
    var = fmaxf(var, 0.f);
    const float rstd = rsqrtf(var + LN_EPS);

    float4 w4 = *(const float4*)&w[c4];
    float4 b4 = *(const float4*)&bb[c4];
    float4 y;
    y.x = w4.x * ((x0 - mean) * rstd) + b4.x;
    y.y = w4.y * ((x1 - mean) * rstd) + b4.y;
    y.z = w4.z * ((x2 - mean) * rstd) + b4.z;
    y.w = w4.w * ((x3 - mean) * rstd) + b4.w;
    *(float4*)&out[row * DMODEL + c4] = y;
}

// ---------------------------------------------------------------
extern "C" void kernel_launch(void* const* d_in, const int* in_sizes, int n_in,
                              void* d_out, int out_size, void* d_ws, size_t ws_size,
                              hipStream_t stream) {
    const float* q_in = (const float*)d_in[0];
    const float* k_in = (const float*)d_in[1];
    const float* v_in = (const float*)d_in[2];
    const float* Wq = (const float*)d_in[3];  const float* bq = (const float*)d_in[4];
    const float* Wk = (const float*)d_in[5];  const float* bk = (const float*)d_in[6];
    const float* Wv = (const float*)d_in[7];  const float* bv = (const float*)d_in[8];
    const float* Wo = (const float*)d_in[9];  const float* bo = (const float*)d_in[10];
    const float* lnw = (const float*)d_in[11]; const float* lnb = (const float*)d_in[12];

    char* wsb = (char*)d_ws;
    unsigned short* QCtx = (unsigned short*)d_out;
    float*          outF = (float*)d_out;
    dim3 blk(256);

    if (ws_size >= (48u << 20)) {
        // fast path: pre-converted bf16 operands
        // ws: [0,24) qb,kb,vb | [24,32) Wqb,Wkb,Wvb,Wob | [32,48) Kb,Vb
        // O32 fp32 overlays [0,16) (input copies dead after qkv)
        unsigned short* qb  = (unsigned short*)(wsb);
        unsigned short* kb  = (unsigned short*)(wsb + (8u  << 20));
        unsigned short* vb  = (unsigned short*)(wsb + (16u << 20));
        unsigned short* Wqb = (unsigned short*)(wsb + (24u << 20));
        unsigned short* Wkb = (unsigned short*)(wsb + (26u << 20));
        unsigned short* Wvb = (unsigned short*)(wsb + (28u << 20));
        unsigned short* Wob = (unsigned short*)(wsb + (30u << 20));
        unsigned short* Kb  = (unsigned short*)(wsb + (32u << 20));
        unsigned short* Vb  = (unsigned short*)(wsb + (40u << 20));
        float*          O32 = (float*)(wsb);

        cvt_kernel<<<dim3(512, 1, 7), blk, 0, stream>>>(
            q_in, k_in, v_in, Wq, Wk, Wv, Wo,
            qb, kb, vb, Wqb, Wkb, Wvb, Wob);
        qkv_bf16<<<dim3(MROWS/128, DMODEL/128, 3), blk, 0, stream>>>(
            qb, kb, vb, Wqb, bq, Wkb, bk, Wvb, bv, QCtx, Kb, Vb);
        attn_mfma<<<dim3(SEQ/64, BATCH*NHEAD), blk, 0, stream>>>(QCtx, Kb, Vb, QCtx);
        oproj_bf16<<<dim3(MROWS/128, DMODEL/128), blk, 0, stream>>>(QCtx, Wob, bo, O32);
        ln2_kernel<<<dim3(MROWS), blk, 0, stream>>>(O32, q_in, lnw, lnb, outF);
    } else if (ws_size >= (16u << 20)) {
        // fallback: round-12 fused-cvt path
        unsigned short* Kb  = (unsigned short*)(wsb);
        unsigned short* Vb  = (unsigned short*)(wsb + (8u << 20));
        float*          O32 = (float*)(wsb);
        qkv_mfma<<<dim3(MROWS/128, DMODEL/128, 3), blk, 0, stream>>>(
            q_in, k_in, v_in, Wq, bq, Wk, bk, Wv, bv, QCtx, Kb, Vb);
        attn_mfma<<<dim3(SEQ/64, BATCH*NHEAD), blk, 0, stream>>>(QCtx, Kb, Vb, QCtx);
        oproj_mfma<<<dim3(MROWS/128, DMODEL/128), blk, 0, stream>>>(QCtx, Wo, bo, O32);
        ln2_kernel<<<dim3(MROWS), blk, 0, stream>>>(O32, q_in, lnw, lnb, outF);
    } else {
        beacon_kernel<<<1, 64, 0, stream>>>((float*)d_out, 300.0f);
    }
}

// Round 14
// 292.185 us; speedup vs baseline: 5.0177x; 1.1756x over previous
//
#include <hip/hip_runtime.h>

#define SEQ    2048
#define BATCH  2
#define DMODEL 1024
#define NHEAD  16
#define DH     64
#define MROWS  (SEQ*BATCH)        // 4096
#define RS     (BATCH*DMODEL)     // 2048
#define LN_EPS 1e-12f

typedef __attribute__((ext_vector_type(8))) short short8;
typedef __attribute__((ext_vector_type(4))) float floatx4;

// ---- bf16 bit helpers (intermediates only; in/out are fp32) ----
__device__ __forceinline__ float bf2f(unsigned short s) {
    union { unsigned u; float f; } a; a.u = ((unsigned)s) << 16; return a.f;
}
__device__ __forceinline__ unsigned short f2bf(float x) {
    union { float f; unsigned u; } a; a.f = x;
    unsigned r = a.u + 0x7fffu + ((a.u >> 16) & 1u);
    return (unsigned short)(r >> 16);
}
__device__ __forceinline__ uint4 cvt8(const float* __restrict__ p) {
    float4 x0 = *(const float4*)(p);
    float4 x1 = *(const float4*)(p + 4);
    union { uint4 u; unsigned short s[8]; } r;
    r.s[0] = f2bf(x0.x); r.s[1] = f2bf(x0.y);
    r.s[2] = f2bf(x0.z); r.s[3] = f2bf(x0.w);
    r.s[4] = f2bf(x1.x); r.s[5] = f2bf(x1.y);
    r.s[6] = f2bf(x1.z); r.s[7] = f2bf(x1.w);
    return r.u;
}

__global__ void beacon_kernel(float* out, float val) {
    if (threadIdx.x == 0) out[0] = val;
}

// ---------------------------------------------------------------
// One-shot fp32 -> bf16 conversion of inputs + weights.
// ---------------------------------------------------------------
__global__ __launch_bounds__(256)
void cvt_kernel(const float* __restrict__ s0, const float* __restrict__ s1,
                const float* __restrict__ s2, const float* __restrict__ s3,
                const float* __restrict__ s4, const float* __restrict__ s5,
                const float* __restrict__ s6,
                unsigned short* __restrict__ d0, unsigned short* __restrict__ d1,
                unsigned short* __restrict__ d2, unsigned short* __restrict__ d3,
                unsigned short* __restrict__ d4, unsigned short* __restrict__ d5,
                unsigned short* __restrict__ d6)
{
    const float* srcs[7] = {s0, s1, s2, s3, s4, s5, s6};
    unsigned short* dsts[7] = {d0, d1, d2, d3, d4, d5, d6};
    const int cnts[7] = {4194304, 4194304, 4194304, 1048576, 1048576, 1048576, 1048576};
    const int z = blockIdx.z;
    const float* src = srcs[z];
    unsigned short* dst = dsts[z];
    const int count = cnts[z];
    const int stride = gridDim.x * 256 * 8;
    for (int i = (blockIdx.x * 256 + threadIdx.x) * 8; i < count; i += stride)
        *(uint4*)&dst[i] = cvt8(&src[i]);
}

// ---------------------------------------------------------------
// bf16 MFMA GEMM (unchanged from round 13)
// ---------------------------------------------------------------
template<int OUTF32>
__device__ __forceinline__ void gemm_bf16_body(
    const unsigned short* __restrict__ A,
    const unsigned short* __restrict__ W,
    const float* __restrict__ bias,
    void* __restrict__ Cout)
{
    __shared__ __align__(16) short Alds[128*32];
    __shared__ __align__(16) short Blds[128*32];

    const int tid  = threadIdx.x;
    const int lane = tid & 63;
    const int wave = tid >> 6;
    const int lrow = lane & 15;
    const int lq   = lane >> 4;
    const int m0 = blockIdx.x * 128;
    const int n0 = blockIdx.y * 128;
    const int mw = (wave >> 1) * 64;
    const int nw = (wave & 1) * 64;
    const int K  = DMODEL;

    floatx4 zero = {0.f, 0.f, 0.f, 0.f};
    floatx4 acc[4][4];
    #pragma unroll
    for (int i = 0; i < 4; ++i)
        #pragma unroll
        for (int j = 0; j < 4; ++j) acc[i][j] = zero;

    for (int k0 = 0; k0 < K; k0 += 32) {
        #pragma unroll
        for (int rep = 0; rep < 2; ++rep) {
            int chunk = tid + rep * 256;
            int row = chunk >> 2;
            int col = (chunk & 3) << 3;
            *(uint4*)&Alds[row*32 + col] = *(const uint4*)&A[(m0 + row) * K + k0 + col];
            *(uint4*)&Blds[row*32 + col] = *(const uint4*)&W[(n0 + row) * K + k0 + col];
        }
        __syncthreads();
        short8 af[4], bfg[4];
        #pragma unroll
        for (int mi = 0; mi < 4; ++mi)
            af[mi] = *(const short8*)&Alds[(mw + mi*16 + lrow)*32 + lq*8];
        #pragma unroll
        for (int ni = 0; ni < 4; ++ni)
            bfg[ni] = *(const short8*)&Blds[(nw + ni*16 + lrow)*32 + lq*8];
        #pragma unroll
        for (int mi = 0; mi < 4; ++mi)
            #pragma unroll
            for (int ni = 0; ni < 4; ++ni)
                acc[mi][ni] = __builtin_amdgcn_mfma_f32_16x16x32_bf16(af[mi], bfg[ni], acc[mi][ni], 0, 0, 0);
        __syncthreads();
    }

    #pragma unroll
    for (int mi = 0; mi < 4; ++mi) {
        #pragma unroll
        for (int ni = 0; ni < 4; ++ni) {
            int n = n0 + nw + ni*16 + lrow;
            float bv_ = bias[n];
            #pragma unroll
            for (int r = 0; r < 4; ++r) {
                int m = m0 + mw + mi*16 + lq*4 + r;
                float v = acc[mi][ni][r] + bv_;
                if (OUTF32) ((float*)Cout)[m * DMODEL + n] = v;
                else ((unsigned short*)Cout)[m * DMODEL + n] = f2bf(v);
            }
        }
    }
}

__global__ __launch_bounds__(256)
void qkv_bf16(const unsigned short* __restrict__ qb, const unsigned short* __restrict__ kb,
              const unsigned short* __restrict__ vb,
              const unsigned short* __restrict__ Wqb, const float* __restrict__ bq,
              const unsigned short* __restrict__ Wkb, const float* __restrict__ bk,
              const unsigned short* __restrict__ Wvb, const float* __restrict__ bv,
              unsigned short* __restrict__ Qo, unsigned short* __restrict__ Ko,
              unsigned short* __restrict__ Vo)
{
    const unsigned short *A, *W; const float* B; unsigned short* C;
    if (blockIdx.z == 0)      { A = qb; W = Wqb; B = bq; C = Qo; }
    else if (blockIdx.z == 1) { A = kb; W = Wkb; B = bk; C = Ko; }
    else                      { A = vb; W = Wvb; B = bv; C = Vo; }
    gemm_bf16_body<0>(A, W, B, C);
}

__global__ __launch_bounds__(256)
void oproj_bf16(const unsigned short* __restrict__ Cx,
                const unsigned short* __restrict__ Wob, const float* __restrict__ bo,
                float* __restrict__ O32)
{
    gemm_bf16_body<1>(Cx, Wob, bo, O32);
}

// ---------------- fallback (fused-cvt) GEMMs ----------------
__global__ __launch_bounds__(256)
void qkv_mfma(const float* __restrict__ q_in, const float* __restrict__ k_in,
              const float* __restrict__ v_in,
              const float* __restrict__ Wq, const float* __restrict__ bq,
              const float* __restrict__ Wk, const float* __restrict__ bk,
              const float* __restrict__ Wv, const float* __restrict__ bv,
              unsigned short* __restrict__ Qo, unsigned short* __restrict__ Ko,
              unsigned short* __restrict__ Vo)
{
    const float *A, *W, *B; unsigned short* C;
    if (blockIdx.z == 0)      { A = q_in; W = Wq; B = bq; C = Qo; }
    else if (blockIdx.z == 1) { A = k_in; W = Wk; B = bk; C = Ko; }
    else                      { A = v_in; W = Wv; B = bv; C = Vo; }

    __shared__ __align__(16) short Alds[128*32];
    __shared__ __align__(16) short Blds[128*32];
    const int tid  = threadIdx.x;
    const int lane = tid & 63;
    const int wave = tid >> 6;
    const int lrow = lane & 15;
    const int lq   = lane >> 4;
    const int m0 = blockIdx.x * 128;
    const int n0 = blockIdx.y * 128;
    const int mw = (wave >> 1) * 64;
    const int nw = (wave & 1) * 64;
    const int K  = DMODEL;

    floatx4 zero = {0.f, 0.f, 0.f, 0.f};
    floatx4 acc[4][4];
    #pragma unroll
    for (int i = 0; i < 4; ++i)
        #pragma unroll
        for (int j = 0; j < 4; ++j) acc[i][j] = zero;

    for (int k0 = 0; k0 < K; k0 += 32) {
        #pragma unroll
        for (int rep = 0; rep < 2; ++rep) {
            int chunk = tid + rep * 256;
            int row = chunk >> 2;
            int col = (chunk & 3) << 3;
            *(uint4*)&Alds[row*32 + col] = cvt8(&A[(m0 + row) * K + k0 + col]);
            *(uint4*)&Blds[row*32 + col] = cvt8(&W[(n0 + row) * K + k0 + col]);
        }
        __syncthreads();
        short8 af[4], bfg[4];
        #pragma unroll
        for (int mi = 0; mi < 4; ++mi)
            af[mi] = *(const short8*)&Alds[(mw + mi*16 + lrow)*32 + lq*8];
        #pragma unroll
        for (int ni = 0; ni < 4; ++ni)
            bfg[ni] = *(const short8*)&Blds[(nw + ni*16 + lrow)*32 + lq*8];
        #pragma unroll
        for (int mi = 0; mi < 4; ++mi)
            #pragma unroll
            for (int ni = 0; ni < 4; ++ni)
                acc[mi][ni] = __builtin_amdgcn_mfma_f32_16x16x32_bf16(af[mi], bfg[ni], acc[mi][ni], 0, 0, 0);
        __syncthreads();
    }

    #pragma unroll
    for (int mi = 0; mi < 4; ++mi) {
        #pragma unroll
        for (int ni = 0; ni < 4; ++ni) {
            int n = n0 + nw + ni*16 + lrow;
            float bv_ = B[n];
            #pragma unroll
            for (int r = 0; r < 4; ++r) {
                int m = m0 + mw + mi*16 + lq*4 + r;
                C[m * DMODEL + n] = f2bf(acc[mi][ni][r] + bv_);
            }
        }
    }
}

__global__ __launch_bounds__(256)
void oproj_mfma(const unsigned short* __restrict__ Cx,
                const float* __restrict__ Wo, const float* __restrict__ bo,
                float* __restrict__ O32)
{
    __shared__ __align__(16) short Alds[128*32];
    __shared__ __align__(16) short Blds[128*32];
    const int tid  = threadIdx.x;
    const int lane = tid & 63;
    const int wave = tid >> 6;
    const int lrow = lane & 15;
    const int lq   = lane >> 4;
    const int m0 = blockIdx.x * 128;
    const int n0 = blockIdx.y * 128;
    const int mw = (wave >> 1) * 64;
    const int nw = (wave & 1) * 64;
    const int K  = DMODEL;

    floatx4 zero = {0.f, 0.f, 0.f, 0.f};
    floatx4 acc[4][4];
    #pragma unroll
    for (int i = 0; i < 4; ++i)
        #pragma unroll
        for (int j = 0; j < 4; ++j) acc[i][j] = zero;

    for (int k0 = 0; k0 < K; k0 += 32) {
        #pragma unroll
        for (int rep = 0; rep < 2; ++rep) {
            int chunk = tid + rep * 256;
            int row = chunk >> 2;
            int col = (chunk & 3) << 3;
            *(uint4*)&Alds[row*32 + col] = *(const uint4*)&Cx[(m0 + row) * K + k0 + col];
            *(uint4*)&Blds[row*32 + col] = cvt8(&Wo[(n0 + row) * K + k0 + col]);
        }
        __syncthreads();
        short8 af[4], bfg[4];
        #pragma unroll
        for (int mi = 0; mi < 4; ++mi)
            af[mi] = *(const short8*)&Alds[(mw + mi*16 + lrow)*32 + lq*8];
        #pragma unroll
        for (int ni = 0; ni < 4; ++ni)
            bfg[ni] = *(const short8*)&Blds[(nw + ni*16 + lrow)*32 + lq*8];
        #pragma unroll
        for (int mi = 0; mi < 4; ++mi)
            #pragma unroll
            for (int ni = 0; ni < 4; ++ni)
                acc[mi][ni] = __builtin_amdgcn_mfma_f32_16x16x32_bf16(af[mi], bfg[ni], acc[mi][ni], 0, 0, 0);
        __syncthreads();
    }

    #pragma unroll
    for (int mi = 0; mi < 4; ++mi) {
        #pragma unroll
        for (int ni = 0; ni < 4; ++ni) {
            int n = n0 + nw + ni*16 + lrow;
            float bv_ = bo[n];
            #pragma unroll
            for (int r = 0; r < 4; ++r) {
                int m = m0 + mw + mi*16 + lq*4 + r;
                O32[m * DMODEL + n] = acc[mi][ni][r] + bv_;
            }
        }
    }
}

// ---------------------------------------------------------------
// MFMA flash attention, S^T orientation (round 14).
//  - S^T = mfma(K-frag, Q-frag): lane's 16 scores all belong to ONE q
//    (col = lane&15), so softmax = in-reg reduce + shfl_xor(16,32).
//  - P written as 4x ds_write_b64 (row-contiguous), read as b128 B-frag.
//  - O^T = mfma(Vt-frag, P-frag): col = q matches softmax lane; alpha
//    rescale lane-local; final store packs 4 consecutive d as b64.
//  - Ps is wave-private: no barrier between P write/read (wave_barrier
//    pins compiler order; same-wave LDS ops are processed in order).
//  - 2 barriers per k-iter (staging protect + staging visible).
// NOTE: reference applies NO 1/sqrt(dh) scaling.
// ---------------------------------------------------------------
__global__ __launch_bounds__(256)
void attn_mfma2(const unsigned short* __restrict__ Q,
                const unsigned short* __restrict__ Kg,
                const unsigned short* __restrict__ V,
                unsigned short* __restrict__ Ctx)
{
    __shared__ __align__(16) short Qs[64*72];
    __shared__ __align__(16) short Ks[64*72];
    __shared__ __align__(16) short Vt[64*72];
    __shared__ __align__(16) short Ps[4][16*72];

    const int tid  = threadIdx.x;
    const int lane = tid & 63;
    const int wave = tid >> 6;
    const int lrow = lane & 15;
    const int lq   = lane >> 4;

    const int q0 = blockIdx.x * 64;
    const int bh = blockIdx.y;
    const int off = (bh >> 4) * DMODEL + (bh & 15) * DH;

    // stage Q tile
    #pragma unroll
    for (int rep = 0; rep < 2; ++rep) {
        int chunk = tid + rep * 256;
        int r = chunk >> 3;
        int c = (chunk & 7) << 3;
        *(uint4*)&Qs[r*72 + c] = *(const uint4*)&Q[(q0 + r) * RS + off + c];
    }
    __syncthreads();

    // hoisted Q B-fragments: B[n=q][k=d], q = wave*16+lrow
    short8 qf[2];
    #pragma unroll
    for (int ks = 0; ks < 2; ++ks)
        qf[ks] = *(const short8*)&Qs[(wave*16 + lrow)*72 + ks*32 + lq*8];

    floatx4 zero = {0.f, 0.f, 0.f, 0.f};
    float m_i = -1e30f, l_i = 0.f;
    floatx4 oacc[4];                    // oacc[ni2][r]: d = ni2*16+lq*4+r
    #pragma unroll
    for (int ni = 0; ni < 4; ++ni) oacc[ni] = zero;

    for (int kt = 0; kt < SEQ/64; ++kt) {
        __syncthreads();               // prior iter's Ks/Vt readers done
        const int kbase = kt * 64;
        #pragma unroll
        for (int rep = 0; rep < 2; ++rep) {
            int chunk = tid + rep * 256;
            int r = chunk >> 3;
            int c = (chunk & 7) << 3;
            *(uint4*)&Ks[r*72 + c] = *(const uint4*)&Kg[(kbase + r) * RS + off + c];
            uint4 vv = *(const uint4*)&V[(kbase + r) * RS + off + c];
            union { uint4 u; short s[8]; } uv; uv.u = vv;
            int swz = (chunk & 7) << 3;
            #pragma unroll
            for (int j = 0; j < 8; ++j)
                Vt[(c + j)*72 + (r ^ swz)] = uv.s[j];
        }
        __syncthreads();

        // ---- S^T = K Q^T : D[m=key][n=q] ----
        floatx4 sacc[4];
        #pragma unroll
        for (int ni = 0; ni < 4; ++ni) sacc[ni] = zero;
        #pragma unroll
        for (int ni = 0; ni < 4; ++ni) {
            #pragma unroll
            for (int ks = 0; ks < 2; ++ks) {
                short8 kf = *(const short8*)&Ks[(ni*16 + lrow)*72 + ks*32 + lq*8];
                sacc[ni] = __builtin_amdgcn_mfma_f32_16x16x32_bf16(kf, qf[ks], sacc[ni], 0, 0, 0);
            }
        }

        // ---- online softmax, lane-local q; keys = ni*16 + lq*4 + r ----
        float mx = sacc[0][0];
        #pragma unroll
        for (int ni = 0; ni < 4; ++ni)
            #pragma unroll
            for (int r = 0; r < 4; ++r) mx = fmaxf(mx, sacc[ni][r]);
        mx = fmaxf(mx, __shfl_xor(mx, 16));
        mx = fmaxf(mx, __shfl_xor(mx, 32));
        float mnew = fmaxf(m_i, mx);
        float alpha = __expf(m_i - mnew);
        float p[4][4];
        float psum = 0.f;
        #pragma unroll
        for (int ni = 0; ni < 4; ++ni)
            #pragma unroll
            for (int r = 0; r < 4; ++r) {
                p[ni][r] = __expf(sacc[ni][r] - mnew);
                psum += p[ni][r];
            }
        psum += __shfl_xor(psum, 16);
        psum += __shfl_xor(psum, 32);
        l_i = l_i * alpha + psum;
        m_i = mnew;
        #pragma unroll
        for (int ni = 0; ni < 4; ++ni)
            #pragma unroll
            for (int r = 0; r < 4; ++r) oacc[ni][r] *= alpha;

        // ---- P write: PsT[q=lrow][key], 4 consecutive keys per b64 ----
        #pragma unroll
        for (int ni = 0; ni < 4; ++ni) {
            uint2 pk;
            pk.x = (unsigned)f2bf(p[ni][0]) | ((unsigned)f2bf(p[ni][1]) << 16);
            pk.y = (unsigned)f2bf(p[ni][2]) | ((unsigned)f2bf(p[ni][3]) << 16);
            *(uint2*)&Ps[wave][lrow*72 + ni*16 + lq*4] = pk;
        }
        __builtin_amdgcn_wave_barrier();   // order wave-private LDS write->read

        // ---- O^T += Vt P^T : D[m=d][n=q] ----
        short8 pf[2];
        #pragma unroll
        for (int ks = 0; ks < 2; ++ks)
            pf[ks] = *(const short8*)&Ps[wave][lrow*72 + ks*32 + lq*8];
        #pragma unroll
        for (int ni = 0; ni < 4; ++ni) {
            #pragma unroll
            for (int ks = 0; ks < 2; ++ks) {
                int d  = ni*16 + lrow;
                int kk = ks*32 + lq*8;
                int swz = ((d >> 3) & 7) << 3;
                short8 vf = *(const short8*)&Vt[d*72 + (kk ^ swz)];
                oacc[ni] = __builtin_amdgcn_mfma_f32_16x16x32_bf16(vf, pf[ks], oacc[ni], 0, 0, 0);
            }
        }
    }

    const float inv = 1.f / l_i;
    const int q = q0 + wave*16 + lrow;
    #pragma unroll
    for (int ni = 0; ni < 4; ++ni) {
        uint2 ok;
        ok.x = (unsigned)f2bf(oacc[ni][0] * inv) | ((unsigned)f2bf(oacc[ni][1] * inv) << 16);
        ok.y = (unsigned)f2bf(oacc[ni][2] * inv) | ((unsigned)f2bf(oacc[ni][3] * inv) << 16);
        *(uint2*)&Ctx[q * RS + off + ni*16 + lq*4] = ok;
    }
}

// ---------------------------------------------------------------
// LayerNorm(out + residual): fp32 in, fp32 out.
// ---------------------------------------------------------------
__global__ __launch_bounds__(256)
void ln2_kernel(const float* __restrict__ O,
                const float* __restrict__ resid,
                const float* __restrict__ w,
                const float* __restrict__ bb,
                float* __restrict__ out)
{
    __shared__ float r1[256];
    __shared__ float r2[256];
    const int row = blockIdx.x;
    const int tid = threadIdx.x;
    const int c4 = tid * 4;

    float4 o4 = *(const float4*)&O[row * DMODEL + c4];
    float4 q4 = *(const float4*)&resid[row * DMODEL + c4];
    float x0 = o4.x + q4.x;
    float x1 = o4.y + q4.y;
    float x2 = o4.z + q4.z;
    float x3 = o4.w + q4.w;

    r1[tid] = x0 + x1 + x2 + x3;
    r2[tid] = x0*x0 + x1*x1 + x2*x2 + x3*x3;
    __syncthreads();
    for (int st = 128; st > 0; st >>= 1) {
        if (tid < st) { r1[tid] += r1[tid + st]; r2[tid] += r2[tid + st]; }
        __syncthreads();
    }
    const float mean = r1[0] * (1.f / DMODEL);
    float var = r2[0] * (1.f / DMODEL) - mean * mean;
    var = fmaxf(var, 0.f);
    const float rstd = rsqrtf(var + LN_EPS);

    float4 w4 = *(const float4*)&w[c4];
    float4 b4 = *(const float4*)&bb[c4];
    float4 y;
    y.x = w4.x * ((x0 - mean) * rstd) + b4.x;
    y.y = w4.y * ((x1 - mean) * rstd) + b4.y;
    y.z = w4.z * ((x2 - mean) * rstd) + b4.z;
    y.w = w4.w * ((x3 - mean) * rstd) + b4.w;
    *(float4*)&out[row * DMODEL + c4] = y;
}

// ---------------------------------------------------------------
extern "C" void kernel_launch(void* const* d_in, const int* in_sizes, int n_in,
                              void* d_out, int out_size, void* d_ws, size_t ws_size,
                              hipStream_t stream) {
    const float* q_in = (const float*)d_in[0];
    const float* k_in = (const float*)d_in[1];
    const float* v_in = (const float*)d_in[2];
    const float* Wq = (const float*)d_in[3];  const float* bq = (const float*)d_in[4];
    const float* Wk = (const float*)d_in[5];  const float* bk = (const float*)d_in[6];
    const float* Wv = (const float*)d_in[7];  const float* bv = (const float*)d_in[8];
    const float* Wo = (const float*)d_in[9];  const float* bo = (const float*)d_in[10];
    const float* lnw = (const float*)d_in[11]; const float* lnb = (const float*)d_in[12];

    char* wsb = (char*)d_ws;
    unsigned short* QCtx = (unsigned short*)d_out;
    float*          outF = (float*)d_out;
    dim3 blk(256);

    if (ws_size >= (48u << 20)) {
        unsigned short* qb  = (unsigned short*)(wsb);
        unsigned short* kb  = (unsigned short*)(wsb + (8u  << 20));
        unsigned short* vb  = (unsigned short*)(wsb + (16u << 20));
        unsigned short* Wqb = (unsigned short*)(wsb + (24u << 20));
        unsigned short* Wkb = (unsigned short*)(wsb + (26u << 20));
        unsigned short* Wvb = (unsigned short*)(wsb + (28u << 20));
        unsigned short* Wob = (unsigned short*)(wsb + (30u << 20));
        unsigned short* Kb  = (unsigned short*)(wsb + (32u << 20));
        unsigned short* Vb  = (unsigned short*)(wsb + (40u << 20));
        float*          O32 = (float*)(wsb);

        cvt_kernel<<<dim3(512, 1, 7), blk, 0, stream>>>(
            q_in, k_in, v_in, Wq, Wk, Wv, Wo,
            qb, kb, vb, Wqb, Wkb, Wvb, Wob);
        qkv_bf16<<<dim3(MROWS/128, DMODEL/128, 3), blk, 0, stream>>>(
            qb, kb, vb, Wqb, bq, Wkb, bk, Wvb, bv, QCtx, Kb, Vb);
        attn_mfma2<<<dim3(SEQ/64, BATCH*NHEAD), blk, 0, stream>>>(QCtx, Kb, Vb, QCtx);
        oproj_bf16<<<dim3(MROWS/128, DMODEL/128), blk, 0, stream>>>(QCtx, Wob, bo, O32);
        ln2_kernel<<<dim3(MROWS), blk, 0, stream>>>(O32, q_in, lnw, lnb, outF);
    } else if (ws_size >= (16u << 20)) {
        unsigned short* Kb  = (unsigned short*)(wsb);
        unsigned short* Vb  = (unsigned short*)(wsb + (8u << 20));
        float*          O32 = (float*)(wsb);
        qkv_mfma<<<dim3(MROWS/128, DMODEL/128, 3), blk, 0, stream>>>(
            q_in, k_in, v_in, Wq, bq, Wk, bk, Wv, bv, QCtx, Kb, Vb);
        attn_mfma2<<<dim3(SEQ/64, BATCH*NHEAD), blk, 0, stream>>>(QCtx, Kb, Vb, QCtx);
        oproj_mfma<<<dim3(MROWS/128, DMODEL/128), blk, 0, stream>>>(QCtx, Wo, bo, O32);
        ln2_kernel<<<dim3(MROWS), blk, 0, stream>>>(O32, q_in, lnw, lnb, outF);
    } else {
        beacon_kernel<<<1, 64, 0, stream>>>((float*)d_out, 300.0f);
    }
}

// Round 15
// 273.690 us; speedup vs baseline: 5.3568x; 1.0676x over previous
//
#include <hip/hip_runtime.h>

#define SEQ    2048
#define BATCH  2
#define DMODEL 1024
#define NHEAD  16
#define DH     64
#define MROWS  (SEQ*BATCH)        // 4096
#define RS     (BATCH*DMODEL)     // 2048
#define LN_EPS 1e-12f

typedef __attribute__((ext_vector_type(8))) short short8;
typedef __attribute__((ext_vector_type(4))) float floatx4;

#define AS_GLOBAL __attribute__((address_space(1)))
#define AS_LDS    __attribute__((address_space(3)))

// ---- bf16 bit helpers (intermediates only; in/out are fp32) ----
__device__ __forceinline__ float bf2f(unsigned short s) {
    union { unsigned u; float f; } a; a.u = ((unsigned)s) << 16; return a.f;
}
__device__ __forceinline__ unsigned short f2bf(float x) {
    union { float f; unsigned u; } a; a.f = x;
    unsigned r = a.u + 0x7fffu + ((a.u >> 16) & 1u);
    return (unsigned short)(r >> 16);
}
__device__ __forceinline__ uint4 cvt8(const float* __restrict__ p) {
    float4 x0 = *(const float4*)(p);
    float4 x1 = *(const float4*)(p + 4);
    union { uint4 u; unsigned short s[8]; } r;
    r.s[0] = f2bf(x0.x); r.s[1] = f2bf(x0.y);
    r.s[2] = f2bf(x0.z); r.s[3] = f2bf(x0.w);
    r.s[4] = f2bf(x1.x); r.s[5] = f2bf(x1.y);
    r.s[6] = f2bf(x1.z); r.s[7] = f2bf(x1.w);
    return r.u;
}

__global__ void beacon_kernel(float* out, float val) {
    if (threadIdx.x == 0) out[0] = val;
}

// ---------------------------------------------------------------
// One-shot fp32 -> bf16 conversion of inputs + weights.
// ---------------------------------------------------------------
__global__ __launch_bounds__(256)
void cvt_kernel(const float* __restrict__ s0, const float* __restrict__ s1,
                const float* __restrict__ s2, const float* __restrict__ s3,
                const float* __restrict__ s4, const float* __restrict__ s5,
                const float* __restrict__ s6,
                unsigned short* __restrict__ d0, unsigned short* __restrict__ d1,
                unsigned short* __restrict__ d2, unsigned short* __restrict__ d3,
                unsigned short* __restrict__ d4, unsigned short* __restrict__ d5,
                unsigned short* __restrict__ d6)
{
    const float* srcs[7] = {s0, s1, s2, s3, s4, s5, s6};
    unsigned short* dsts[7] = {d0, d1, d2, d3, d4, d5, d6};
    const int cnts[7] = {4194304, 4194304, 4194304, 1048576, 1048576, 1048576, 1048576};
    const int z = blockIdx.z;
    const float* src = srcs[z];
    unsigned short* dst = dsts[z];
    const int count = cnts[z];
    const int stride = gridDim.x * 256 * 8;
    for (int i = (blockIdx.x * 256 + threadIdx.x) * 8; i < count; i += stride)
        *(uint4*)&dst[i] = cvt8(&src[i]);
}

// ---------------------------------------------------------------
// bf16 MFMA GEMM with async global->LDS staging (width=16).
// LDS layout is lane-linear (chunk*16B, wave-contiguous) so the
// wave-uniform-base + lane*16 contract of global_load_lds matches
// the old layout exactly (element offset chunk*8 == row*32+col).
// ---------------------------------------------------------------
template<int OUTF32>
__device__ __forceinline__ void gemm_bf16_body(
    const unsigned short* __restrict__ A,
    const unsigned short* __restrict__ W,
    const float* __restrict__ bias,
    void* __restrict__ Cout)
{
    __shared__ __align__(16) short Alds[128*32];
    __shared__ __align__(16) short Blds[128*32];

    const int tid  = threadIdx.x;
    const int lane = tid & 63;
    const int wave = tid >> 6;
    const int lrow = lane & 15;
    const int lq   = lane >> 4;
    const int m0 = blockIdx.x * 128;
    const int n0 = blockIdx.y * 128;
    const int mw = (wave >> 1) * 64;
    const int nw = (wave & 1) * 64;
    const int K  = DMODEL;

    // staging coordinates (two 16B chunks per thread per operand)
    const int chunk0 = tid;
    const int chunk1 = tid + 256;
    const int row0 = chunk0 >> 2, col0 = (chunk0 & 3) << 3;
    const int row1 = chunk1 >> 2, col1 = (chunk1 & 3) << 3;
    const unsigned short* gA0 = &A[(m0 + row0) * K + col0];
    const unsigned short* gA1 = &A[(m0 + row1) * K + col1];
    const unsigned short* gB0 = &W[(n0 + row0) * K + col0];
    const unsigned short* gB1 = &W[(n0 + row1) * K + col1];
    // wave-uniform LDS bases: element (chunkbase)*8
    AS_LDS unsigned int* lA0 = (AS_LDS unsigned int*)&Alds[(wave*64)*8];
    AS_LDS unsigned int* lA1 = (AS_LDS unsigned int*)&Alds[(256 + wave*64)*8];
    AS_LDS unsigned int* lB0 = (AS_LDS unsigned int*)&Blds[(wave*64)*8];
    AS_LDS unsigned int* lB1 = (AS_LDS unsigned int*)&Blds[(256 + wave*64)*8];

    floatx4 zero = {0.f, 0.f, 0.f, 0.f};
    floatx4 acc[4][4];
    #pragma unroll
    for (int i = 0; i < 4; ++i)
        #pragma unroll
        for (int j = 0; j < 4; ++j) acc[i][j] = zero;

    for (int k0 = 0; k0 < K; k0 += 32) {
        __builtin_amdgcn_global_load_lds((const AS_GLOBAL unsigned int*)(gA0 + k0), lA0, 16, 0, 0);
        __builtin_amdgcn_global_load_lds((const AS_GLOBAL unsigned int*)(gA1 + k0), lA1, 16, 0, 0);
        __builtin_amdgcn_global_load_lds((const AS_GLOBAL unsigned int*)(gB0 + k0), lB0, 16, 0, 0);
        __builtin_amdgcn_global_load_lds((const AS_GLOBAL unsigned int*)(gB1 + k0), lB1, 16, 0, 0);
        __syncthreads();                       // drains vmcnt + barrier
        short8 af[4], bfg[4];
        #pragma unroll
        for (int mi = 0; mi < 4; ++mi)
            af[mi] = *(const short8*)&Alds[(mw + mi*16 + lrow)*32 + lq*8];
        #pragma unroll
        for (int ni = 0; ni < 4; ++ni)
            bfg[ni] = *(const short8*)&Blds[(nw + ni*16 + lrow)*32 + lq*8];
        #pragma unroll
        for (int mi = 0; mi < 4; ++mi)
            #pragma unroll
            for (int ni = 0; ni < 4; ++ni)
                acc[mi][ni] = __builtin_amdgcn_mfma_f32_16x16x32_bf16(af[mi], bfg[ni], acc[mi][ni], 0, 0, 0);
        __syncthreads();
    }

    #pragma unroll
    for (int mi = 0; mi < 4; ++mi) {
        #pragma unroll
        for (int ni = 0; ni < 4; ++ni) {
            int n = n0 + nw + ni*16 + lrow;
            float bv_ = bias[n];
            #pragma unroll
            for (int r = 0; r < 4; ++r) {
                int m = m0 + mw + mi*16 + lq*4 + r;
                float v = acc[mi][ni][r] + bv_;
                if (OUTF32) ((float*)Cout)[m * DMODEL + n] = v;
                else ((unsigned short*)Cout)[m * DMODEL + n] = f2bf(v);
            }
        }
    }
}

__global__ __launch_bounds__(256)
void qkv_bf16(const unsigned short* __restrict__ qb, const unsigned short* __restrict__ kb,
              const unsigned short* __restrict__ vb,
              const unsigned short* __restrict__ Wqb, const float* __restrict__ bq,
              const unsigned short* __restrict__ Wkb, const float* __restrict__ bk,
              const unsigned short* __restrict__ Wvb, const float* __restrict__ bv,
              unsigned short* __restrict__ Qo, unsigned short* __restrict__ Ko,
              unsigned short* __restrict__ Vo)
{
    const unsigned short *A, *W; const float* B; unsigned short* C;
    if (blockIdx.z == 0)      { A = qb; W = Wqb; B = bq; C = Qo; }
    else if (blockIdx.z == 1) { A = kb; W = Wkb; B = bk; C = Ko; }
    else                      { A = vb; W = Wvb; B = bv; C = Vo; }
    gemm_bf16_body<0>(A, W, B, C);
}

__global__ __launch_bounds__(256)
void oproj_bf16(const unsigned short* __restrict__ Cx,
                const unsigned short* __restrict__ Wob, const float* __restrict__ bo,
                float* __restrict__ O32)
{
    gemm_bf16_body<1>(Cx, Wob, bo, O32);
}

// ---------------- fallback (fused-cvt) GEMMs ----------------
__global__ __launch_bounds__(256)
void qkv_mfma(const float* __restrict__ q_in, const float* __restrict__ k_in,
              const float* __restrict__ v_in,
              const float* __restrict__ Wq, const float* __restrict__ bq,
              const float* __restrict__ Wk, const float* __restrict__ bk,
              const float* __restrict__ Wv, const float* __restrict__ bv,
              unsigned short* __restrict__ Qo, unsigned short* __restrict__ Ko,
              unsigned short* __restrict__ Vo)
{
    const float *A, *W, *B; unsigned short* C;
    if (blockIdx.z == 0)      { A = q_in; W = Wq; B = bq; C = Qo; }
    else if (blockIdx.z == 1) { A = k_in; W = Wk; B = bk; C = Ko; }
    else                      { A = v_in; W = Wv; B = bv; C = Vo; }

    __shared__ __align__(16) short Alds[128*32];
    __shared__ __align__(16) short Blds[128*32];
    const int tid  = threadIdx.x;
    const int lane = tid & 63;
    const int wave = tid >> 6;
    const int lrow = lane & 15;
    const int lq   = lane >> 4;
    const int m0 = blockIdx.x * 128;
    const int n0 = blockIdx.y * 128;
    const int mw = (wave >> 1) * 64;
    const int nw = (wave & 1) * 64;
    const int K  = DMODEL;

    floatx4 zero = {0.f, 0.f, 0.f, 0.f};
    floatx4 acc[4][4];
    #pragma unroll
    for (int i = 0; i < 4; ++i)
        #pragma unroll
        for (int j = 0; j < 4; ++j) acc[i][j] = zero;

    for (int k0 = 0; k0 < K; k0 += 32) {
        #pragma unroll
        for (int rep = 0; rep < 2; ++rep) {
            int chunk = tid + rep * 256;
            int row = chunk >> 2;
            int col = (chunk & 3) << 3;
            *(uint4*)&Alds[row*32 + col] = cvt8(&A[(m0 + row) * K + k0 + col]);
            *(uint4*)&Blds[row*32 + col] = cvt8(&W[(n0 + row) * K + k0 + col]);
        }
        __syncthreads();
        short8 af[4], bfg[4];
        #pragma unroll
        for (int mi = 0; mi < 4; ++mi)
            af[mi] = *(const short8*)&Alds[(mw + mi*16 + lrow)*32 + lq*8];
        #pragma unroll
        for (int ni = 0; ni < 4; ++ni)
            bfg[ni] = *(const short8*)&Blds[(nw + ni*16 + lrow)*32 + lq*8];
        #pragma unroll
        for (int mi = 0; mi < 4; ++mi)
            #pragma unroll
            for (int ni = 0; ni < 4; ++ni)
                acc[mi][ni] = __builtin_amdgcn_mfma_f32_16x16x32_bf16(af[mi], bfg[ni], acc[mi][ni], 0, 0, 0);
        __syncthreads();
    }

    #pragma unroll
    for (int mi = 0; mi < 4; ++mi) {
        #pragma unroll
        for (int ni = 0; ni < 4; ++ni) {
            int n = n0 + nw + ni*16 + lrow;
            float bv_ = B[n];
            #pragma unroll
            for (int r = 0; r < 4; ++r) {
                int m = m0 + mw + mi*16 + lq*4 + r;
                C[m * DMODEL + n] = f2bf(acc[mi][ni][r] + bv_);
            }
        }
    }
}

__global__ __launch_bounds__(256)
void oproj_mfma(const unsigned short* __restrict__ Cx,
                const float* __restrict__ Wo, const float* __restrict__ bo,
                float* __restrict__ O32)
{
    __shared__ __align__(16) short Alds[128*32];
    __shared__ __align__(16) short Blds[128*32];
    const int tid  = threadIdx.x;
    const int lane = tid & 63;
    const int wave = tid >> 6;
    const int lrow = lane & 15;
    const int lq   = lane >> 4;
    const int m0 = blockIdx.x * 128;
    const int n0 = blockIdx.y * 128;
    const int mw = (wave >> 1) * 64;
    const int nw = (wave & 1) * 64;
    const int K  = DMODEL;

    floatx4 zero = {0.f, 0.f, 0.f, 0.f};
    floatx4 acc[4][4];
    #pragma unroll
    for (int i = 0; i < 4; ++i)
        #pragma unroll
        for (int j = 0; j < 4; ++j) acc[i][j] = zero;

    for (int k0 = 0; k0 < K; k0 += 32) {
        #pragma unroll
        for (int rep = 0; rep < 2; ++rep) {
            int chunk = tid + rep * 256;
            int row = chunk >> 2;
            int col = (chunk & 3) << 3;
            *(uint4*)&Alds[row*32 + col] = *(const uint4*)&Cx[(m0 + row) * K + k0 + col];
            *(uint4*)&Blds[row*32 + col] = cvt8(&Wo[(n0 + row) * K + k0 + col]);
        }
        __syncthreads();
        short8 af[4], bfg[4];
        #pragma unroll
        for (int mi = 0; mi < 4; ++mi)
            af[mi] = *(const short8*)&Alds[(mw + mi*16 + lrow)*32 + lq*8];
        #pragma unroll
        for (int ni = 0; ni < 4; ++ni)
            bfg[ni] = *(const short8*)&Blds[(nw + ni*16 + lrow)*32 + lq*8];
        #pragma unroll
        for (int mi = 0; mi < 4; ++mi)
            #pragma unroll
            for (int ni = 0; ni < 4; ++ni)
                acc[mi][ni] = __builtin_amdgcn_mfma_f32_16x16x32_bf16(af[mi], bfg[ni], acc[mi][ni], 0, 0, 0);
        __syncthreads();
    }

    #pragma unroll
    for (int mi = 0; mi < 4; ++mi) {
        #pragma unroll
        for (int ni = 0; ni < 4; ++ni) {
            int n = n0 + nw + ni*16 + lrow;
            float bv_ = bo[n];
            #pragma unroll
            for (int r = 0; r < 4; ++r) {
                int m = m0 + mw + mi*16 + lq*4 + r;
                O32[m * DMODEL + n] = acc[mi][ni][r] + bv_;
            }
        }
    }
}

// ---------------------------------------------------------------
// MFMA flash attention, S^T orientation (unchanged from round 14).
// ---------------------------------------------------------------
__global__ __launch_bounds__(256)
void attn_mfma2(const unsigned short* __restrict__ Q,
                const unsigned short* __restrict__ Kg,
                const unsigned short* __restrict__ V,
                unsigned short* __restrict__ Ctx)
{
    __shared__ __align__(16) short Qs[64*72];
    __shared__ __align__(16) short Ks[64*72];
    __shared__ __align__(16) short Vt[64*72];
    __shared__ __align__(16) short Ps[4][16*72];

    const int tid  = threadIdx.x;
    const int lane = tid & 63;
    const int wave = tid >> 6;
    const int lrow = lane & 15;
    const int lq   = lane >> 4;

    const int q0 = blockIdx.x * 64;
    const int bh = blockIdx.y;
    const int off = (bh >> 4) * DMODEL + (bh & 15) * DH;

    #pragma unroll
    for (int rep = 0; rep < 2; ++rep) {
        int chunk = tid + rep * 256;
        int r = chunk >> 3;
        int c = (chunk & 7) << 3;
        *(uint4*)&Qs[r*72 + c] = *(const uint4*)&Q[(q0 + r) * RS + off + c];
    }
    __syncthreads();

    short8 qf[2];
    #pragma unroll
    for (int ks = 0; ks < 2; ++ks)
        qf[ks] = *(const short8*)&Qs[(wave*16 + lrow)*72 + ks*32 + lq*8];

    floatx4 zero = {0.f, 0.f, 0.f, 0.f};
    float m_i = -1e30f, l_i = 0.f;
    floatx4 oacc[4];
    #pragma unroll
    for (int ni = 0; ni < 4; ++ni) oacc[ni] = zero;

    for (int kt = 0; kt < SEQ/64; ++kt) {
        __syncthreads();
        const int kbase = kt * 64;
        #pragma unroll
        for (int rep = 0; rep < 2; ++rep) {
            int chunk = tid + rep * 256;
            int r = chunk >> 3;
            int c = (chunk & 7) << 3;
            *(uint4*)&Ks[r*72 + c] = *(const uint4*)&Kg[(kbase + r) * RS + off + c];
            uint4 vv = *(const uint4*)&V[(kbase + r) * RS + off + c];
            union { uint4 u; short s[8]; } uv; uv.u = vv;
            int swz = (chunk & 7) << 3;
            #pragma unroll
            for (int j = 0; j < 8; ++j)
                Vt[(c + j)*72 + (r ^ swz)] = uv.s[j];
        }
        __syncthreads();

        floatx4 sacc[4];
        #pragma unroll
        for (int ni = 0; ni < 4; ++ni) sacc[ni] = zero;
        #pragma unroll
        for (int ni = 0; ni < 4; ++ni) {
            #pragma unroll
            for (int ks = 0; ks < 2; ++ks) {
                short8 kf = *(const short8*)&Ks[(ni*16 + lrow)*72 + ks*32 + lq*8];
                sacc[ni] = __builtin_amdgcn_mfma_f32_16x16x32_bf16(kf, qf[ks], sacc[ni], 0, 0, 0);
            }
        }

        float mx = sacc[0][0];
        #pragma unroll
        for (int ni = 0; ni < 4; ++ni)
            #pragma unroll
            for (int r = 0; r < 4; ++r) mx = fmaxf(mx, sacc[ni][r]);
        mx = fmaxf(mx, __shfl_xor(mx, 16));
        mx = fmaxf(mx, __shfl_xor(mx, 32));
        float mnew = fmaxf(m_i, mx);
        float alpha = __expf(m_i - mnew);
        float p[4][4];
        float psum = 0.f;
        #pragma unroll
        for (int ni = 0; ni < 4; ++ni)
            #pragma unroll
            for (int r = 0; r < 4; ++r) {
                p[ni][r] = __expf(sacc[ni][r] - mnew);
                psum += p[ni][r];
            }
        psum += __shfl_xor(psum, 16);
        psum += __shfl_xor(psum, 32);
        l_i = l_i * alpha + psum;
        m_i = mnew;
        #pragma unroll
        for (int ni = 0; ni < 4; ++ni)
            #pragma unroll
            for (int r = 0; r < 4; ++r) oacc[ni][r] *= alpha;

        #pragma unroll
        for (int ni = 0; ni < 4; ++ni) {
            uint2 pk;
            pk.x = (unsigned)f2bf(p[ni][0]) | ((unsigned)f2bf(p[ni][1]) << 16);
            pk.y = (unsigned)f2bf(p[ni][2]) | ((unsigned)f2bf(p[ni][3]) << 16);
            *(uint2*)&Ps[wave][lrow*72 + ni*16 + lq*4] = pk;
        }
        __builtin_amdgcn_wave_barrier();

        short8 pf[2];
        #pragma unroll
        for (int ks = 0; ks < 2; ++ks)
            pf[ks] = *(const short8*)&Ps[wave][lrow*72 + ks*32 + lq*8];
        #pragma unroll
        for (int ni = 0; ni < 4; ++ni) {
            #pragma unroll
            for (int ks = 0; ks < 2; ++ks) {
                int d  = ni*16 + lrow;
                int kk = ks*32 + lq*8;
                int swz = ((d >> 3) & 7) << 3;
                short8 vf = *(const short8*)&Vt[d*72 + (kk ^ swz)];
                oacc[ni] = __builtin_amdgcn_mfma_f32_16x16x32_bf16(vf, pf[ks], oacc[ni], 0, 0, 0);
            }
        }
    }

    const float inv = 1.f / l_i;
    const int q = q0 + wave*16 + lrow;
    #pragma unroll
    for (int ni = 0; ni < 4; ++ni) {
        uint2 ok;
        ok.x = (unsigned)f2bf(oacc[ni][0] * inv) | ((unsigned)f2bf(oacc[ni][1] * inv) << 16);
        ok.y = (unsigned)f2bf(oacc[ni][2] * inv) | ((unsigned)f2bf(oacc[ni][3] * inv) << 16);
        *(uint2*)&Ctx[q * RS + off + ni*16 + lq*4] = ok;
    }
}

// ---------------------------------------------------------------
// LayerNorm(out + residual): fp32 in, fp32 out.
// ---------------------------------------------------------------
__global__ __launch_bounds__(256)
void ln2_kernel(const float* __restrict__ O,
                const float* __restrict__ resid,
                const float* __restrict__ w,
                const float* __restrict__ bb,
                float* __restrict__ out)
{
    __shared__ float r1[256];
    __shared__ float r2[256];
    const int row = blockIdx.x;
    const int tid = threadIdx.x;
    const int c4 = tid * 4;

    float4 o4 = *(const float4*)&O[row * DMODEL + c4];
    float4 q4 = *(const float4*)&resid[row * DMODEL + c4];
    float x0 = o4.x + q4.x;
    float x1 = o4.y + q4.y;
    float x2 = o4.z + q4.z;
    float x3 = o4.w + q4.w;

    r1[tid] = x0 + x1 + x2 + x3;
    r2[tid] = x0*x0 + x1*x1 + x2*x2 + x3*x3;
    __syncthreads();
    for (int st = 128; st > 0; st >>= 1) {
        if (tid < st) { r1[tid] += r1[tid + st]; r2[tid] += r2[tid + st]; }
        __syncthreads();
    }
    const float mean = r1[0] * (1.f / DMODEL);
    float var = r2[0] * (1.f / DMODEL) - mean * mean;
    var = fmaxf(var, 0.f);
    const float rstd = rsqrtf(var + LN_EPS);

    float4 w4 = *(const float4*)&w[c4];
    float4 b4 = *(const float4*)&bb[c4];
    float4 y;
    y.x = w4.x * ((x0 - mean) * rstd) + b4.x;
    y.y = w4.y * ((x1 - mean) * rstd) + b4.y;
    y.z = w4.z * ((x2 - mean) * rstd) + b4.z;
    y.w = w4.w * ((x3 - mean) * rstd) + b4.w;
    *(float4*)&out[row * DMODEL + c4] = y;
}

// ---------------------------------------------------------------
extern "C" void kernel_launch(void* const* d_in, const int* in_sizes, int n_in,
                              void* d_out, int out_size, void* d_ws, size_t ws_size,
                              hipStream_t stream) {
    const float* q_in = (const float*)d_in[0];
    const float* k_in = (const float*)d_in[1];
    const float* v_in = (const float*)d_in[2];
    const float* Wq = (const float*)d_in[3];  const float* bq = (const float*)d_in[4];
    const float* Wk = (const float*)d_in[5];  const float* bk = (const float*)d_in[6];
    const float* Wv = (const float*)d_in[7];  const float* bv = (const float*)d_in[8];
    const float* Wo = (const float*)d_in[9];  const float* bo = (const float*)d_in[10];
    const float* lnw = (const float*)d_in[11]; const float* lnb = (const float*)d_in[12];

    char* wsb = (char*)d_ws;
    unsigned short* QCtx = (unsigned short*)d_out;
    float*          outF = (float*)d_out;
    dim3 blk(256);

    if (ws_size >= (48u << 20)) {
        unsigned short* qb  = (unsigned short*)(wsb);
        unsigned short* kb  = (unsigned short*)(wsb + (8u  << 20));
        unsigned short* vb  = (unsigned short*)(wsb + (16u << 20));
        unsigned short* Wqb = (unsigned short*)(wsb + (24u << 20));
        unsigned short* Wkb = (unsigned short*)(wsb + (26u << 20));
        unsigned short* Wvb = (unsigned short*)(wsb + (28u << 20));
        unsigned short* Wob = (unsigned short*)(wsb + (30u << 20));
        unsigned short* Kb  = (unsigned short*)(wsb + (32u << 20));
        unsigned short* Vb  = (unsigned short*)(wsb + (40u << 20));
        float*          O32 = (float*)(wsb);

        cvt_kernel<<<dim3(512, 1, 7), blk, 0, stream>>>(
            q_in, k_in, v_in, Wq, Wk, Wv, Wo,
            qb, kb, vb, Wqb, Wkb, Wvb, Wob);
        qkv_bf16<<<dim3(MROWS/128, DMODEL/128, 3), blk, 0, stream>>>(
            qb, kb, vb, Wqb, bq, Wkb, bk, Wvb, bv, QCtx, Kb, Vb);
        attn_mfma2<<<dim3(SEQ/64, BATCH*NHEAD), blk, 0, stream>>>(QCtx, Kb, Vb, QCtx);
        oproj_bf16<<<dim3(MROWS/128, DMODEL/128), blk, 0, stream>>>(QCtx, Wob, bo, O32);
        ln2_kernel<<<dim3(MROWS), blk, 0, stream>>>(O32, q_in, lnw, lnb, outF);
    } else if (ws_size >= (16u << 20)) {
        unsigned short* Kb  = (unsigned short*)(wsb);
        unsigned short* Vb  = (unsigned short*)(wsb + (8u << 20));
        float*          O32 = (float*)(wsb);
        qkv_mfma<<<dim3(MROWS/128, DMODEL/128, 3), blk, 0, stream>>>(
            q_in, k_in, v_in, Wq, bq, Wk, bk, Wv, bv, QCtx, Kb, Vb);
        attn_mfma2<<<dim3(SEQ/64, BATCH*NHEAD), blk, 0, stream>>>(QCtx, Kb, Vb, QCtx);
        oproj_mfma<<<dim3(MROWS/128, DMODEL/128), blk, 0, stream>>>(QCtx, Wo, bo, O32);
        ln2_kernel<<<dim3(MROWS), blk, 0, stream>>>(O32, q_in, lnw, lnb, outF);
    } else {
        beacon_kernel<<<1, 64, 0, stream>>>((float*)d_out, 300.0f);
    }
}

// Round 16
// 270.183 us; speedup vs baseline: 5.4263x; 1.0130x over previous
//
#include <hip/hip_runtime.h>

#define SEQ    2048
#define BATCH  2
#define DMODEL 1024
#define NHEAD  16
#define DH     64
#define MROWS  (SEQ*BATCH)        // 4096
#define RS     (BATCH*DMODEL)     // 2048
#define LN_EPS 1e-12f

typedef __attribute__((ext_vector_type(8))) short short8;
typedef __attribute__((ext_vector_type(4))) float floatx4;

#define AS_GLOBAL __attribute__((address_space(1)))
#define AS_LDS    __attribute__((address_space(3)))

// ---- bf16 bit helpers (intermediates only; in/out are fp32) ----
__device__ __forceinline__ float bf2f(unsigned short s) {
    union { unsigned u; float f; } a; a.u = ((unsigned)s) << 16; return a.f;
}
__device__ __forceinline__ unsigned short f2bf(float x) {
    union { float f; unsigned u; } a; a.f = x;
    unsigned r = a.u + 0x7fffu + ((a.u >> 16) & 1u);
    return (unsigned short)(r >> 16);
}
__device__ __forceinline__ uint4 cvt8(const float* __restrict__ p) {
    float4 x0 = *(const float4*)(p);
    float4 x1 = *(const float4*)(p + 4);
    union { uint4 u; unsigned short s[8]; } r;
    r.s[0] = f2bf(x0.x); r.s[1] = f2bf(x0.y);
    r.s[2] = f2bf(x0.z); r.s[3] = f2bf(x0.w);
    r.s[4] = f2bf(x1.x); r.s[5] = f2bf(x1.y);
    r.s[6] = f2bf(x1.z); r.s[7] = f2bf(x1.w);
    return r.u;
}

__global__ void beacon_kernel(float* out, float val) {
    if (threadIdx.x == 0) out[0] = val;
}

// ---------------------------------------------------------------
// One-shot fp32 -> bf16 conversion of inputs + weights.
// ---------------------------------------------------------------
__global__ __launch_bounds__(256)
void cvt_kernel(const float* __restrict__ s0, const float* __restrict__ s1,
                const float* __restrict__ s2, const float* __restrict__ s3,
                const float* __restrict__ s4, const float* __restrict__ s5,
                const float* __restrict__ s6,
                unsigned short* __restrict__ d0, unsigned short* __restrict__ d1,
                unsigned short* __restrict__ d2, unsigned short* __restrict__ d3,
                unsigned short* __restrict__ d4, unsigned short* __restrict__ d5,
                unsigned short* __restrict__ d6)
{
    const float* srcs[7] = {s0, s1, s2, s3, s4, s5, s6};
    unsigned short* dsts[7] = {d0, d1, d2, d3, d4, d5, d6};
    const int cnts[7] = {4194304, 4194304, 4194304, 1048576, 1048576, 1048576, 1048576};
    const int z = blockIdx.z;
    const float* src = srcs[z];
    unsigned short* dst = dsts[z];
    const int count = cnts[z];
    const int stride = gridDim.x * 256 * 8;
    for (int i = (blockIdx.x * 256 + threadIdx.x) * 8; i < count; i += stride)
        *(uint4*)&dst[i] = cvt8(&src[i]);
}

// ---------------------------------------------------------------
// V transpose: Vb [token=(s*2+b)][dmodel] -> VT [bh=32][d=64][s=2048]
// One 64s x 64d tile per block via padded LDS. ~16 MB traffic.
// ---------------------------------------------------------------
__global__ __launch_bounds__(256)
void vt_kernel(const unsigned short* __restrict__ Vb,
               unsigned short* __restrict__ VT)
{
    __shared__ __align__(16) short T[64*72];
    const int tid = threadIdx.x;
    const int s0 = blockIdx.x * 64;
    const int bh = blockIdx.y;
    const int b = bh >> 4, h = bh & 15;

    #pragma unroll
    for (int rep = 0; rep < 2; ++rep) {
        int c = tid + rep * 256;
        int s = c >> 3, cc = c & 7;
        *(uint4*)&T[s*72 + cc*8] =
            *(const uint4*)&Vb[((s0 + s) * BATCH + b) * DMODEL + h*64 + cc*8];
    }
    __syncthreads();
    #pragma unroll
    for (int rep = 0; rep < 2; ++rep) {
        int o = tid + rep * 256;
        int d = o >> 3, sc = o & 7;
        union { uint4 u; unsigned short e[8]; } pk;
        #pragma unroll
        for (int j = 0; j < 8; ++j)
            pk.e[j] = (unsigned short)T[(sc*8 + j)*72 + d];
        *(uint4*)&VT[bh*(DH*SEQ) + d*SEQ + s0 + sc*8] = pk.u;
    }
}

// ---------------------------------------------------------------
// bf16 MFMA GEMM with async global->LDS staging (round 15).
// ---------------------------------------------------------------
template<int OUTF32>
__device__ __forceinline__ void gemm_bf16_body(
    const unsigned short* __restrict__ A,
    const unsigned short* __restrict__ W,
    const float* __restrict__ bias,
    void* __restrict__ Cout)
{
    __shared__ __align__(16) short Alds[128*32];
    __shared__ __align__(16) short Blds[128*32];

    const int tid  = threadIdx.x;
    const int lane = tid & 63;
    const int wave = tid >> 6;
    const int lrow = lane & 15;
    const int lq   = lane >> 4;
    const int m0 = blockIdx.x * 128;
    const int n0 = blockIdx.y * 128;
    const int mw = (wave >> 1) * 64;
    const int nw = (wave & 1) * 64;
    const int K  = DMODEL;

    const int chunk0 = tid;
    const int chunk1 = tid + 256;
    const int row0 = chunk0 >> 2, col0 = (chunk0 & 3) << 3;
    const int row1 = chunk1 >> 2, col1 = (chunk1 & 3) << 3;
    const unsigned short* gA0 = &A[(m0 + row0) * K + col0];
    const unsigned short* gA1 = &A[(m0 + row1) * K + col1];
    const unsigned short* gB0 = &W[(n0 + row0) * K + col0];
    const unsigned short* gB1 = &W[(n0 + row1) * K + col1];
    AS_LDS unsigned int* lA0 = (AS_LDS unsigned int*)&Alds[(wave*64)*8];
    AS_LDS unsigned int* lA1 = (AS_LDS unsigned int*)&Alds[(256 + wave*64)*8];
    AS_LDS unsigned int* lB0 = (AS_LDS unsigned int*)&Blds[(wave*64)*8];
    AS_LDS unsigned int* lB1 = (AS_LDS unsigned int*)&Blds[(256 + wave*64)*8];

    floatx4 zero = {0.f, 0.f, 0.f, 0.f};
    floatx4 acc[4][4];
    #pragma unroll
    for (int i = 0; i < 4; ++i)
        #pragma unroll
        for (int j = 0; j < 4; ++j) acc[i][j] = zero;

    for (int k0 = 0; k0 < K; k0 += 32) {
        __builtin_amdgcn_global_load_lds((const AS_GLOBAL unsigned int*)(gA0 + k0), lA0, 16, 0, 0);
        __builtin_amdgcn_global_load_lds((const AS_GLOBAL unsigned int*)(gA1 + k0), lA1, 16, 0, 0);
        __builtin_amdgcn_global_load_lds((const AS_GLOBAL unsigned int*)(gB0 + k0), lB0, 16, 0, 0);
        __builtin_amdgcn_global_load_lds((const AS_GLOBAL unsigned int*)(gB1 + k0), lB1, 16, 0, 0);
        __syncthreads();
        short8 af[4], bfg[4];
        #pragma unroll
        for (int mi = 0; mi < 4; ++mi)
            af[mi] = *(const short8*)&Alds[(mw + mi*16 + lrow)*32 + lq*8];
        #pragma unroll
        for (int ni = 0; ni < 4; ++ni)
            bfg[ni] = *(const short8*)&Blds[(nw + ni*16 + lrow)*32 + lq*8];
        #pragma unroll
        for (int mi = 0; mi < 4; ++mi)
            #pragma unroll
            for (int ni = 0; ni < 4; ++ni)
                acc[mi][ni] = __builtin_amdgcn_mfma_f32_16x16x32_bf16(af[mi], bfg[ni], acc[mi][ni], 0, 0, 0);
        __syncthreads();
    }

    #pragma unroll
    for (int mi = 0; mi < 4; ++mi) {
        #pragma unroll
        for (int ni = 0; ni < 4; ++ni) {
            int n = n0 + nw + ni*16 + lrow;
            float bv_ = bias[n];
            #pragma unroll
            for (int r = 0; r < 4; ++r) {
                int m = m0 + mw + mi*16 + lq*4 + r;
                float v = acc[mi][ni][r] + bv_;
                if (OUTF32) ((float*)Cout)[m * DMODEL + n] = v;
                else ((unsigned short*)Cout)[m * DMODEL + n] = f2bf(v);
            }
        }
    }
}

__global__ __launch_bounds__(256)
void qkv_bf16(const unsigned short* __restrict__ qb, const unsigned short* __restrict__ kb,
              const unsigned short* __restrict__ vb,
              const unsigned short* __restrict__ Wqb, const float* __restrict__ bq,
              const unsigned short* __restrict__ Wkb, const float* __restrict__ bk,
              const unsigned short* __restrict__ Wvb, const float* __restrict__ bv,
              unsigned short* __restrict__ Qo, unsigned short* __restrict__ Ko,
              unsigned short* __restrict__ Vo)
{
    const unsigned short *A, *W; const float* B; unsigned short* C;
    if (blockIdx.z == 0)      { A = qb; W = Wqb; B = bq; C = Qo; }
    else if (blockIdx.z == 1) { A = kb; W = Wkb; B = bk; C = Ko; }
    else                      { A = vb; W = Wvb; B = bv; C = Vo; }
    gemm_bf16_body<0>(A, W, B, C);
}

__global__ __launch_bounds__(256)
void oproj_bf16(const unsigned short* __restrict__ Cx,
                const unsigned short* __restrict__ Wob, const float* __restrict__ bo,
                float* __restrict__ O32)
{
    gemm_bf16_body<1>(Cx, Wob, bo, O32);
}

// ---------------- fallback (fused-cvt) GEMMs ----------------
__global__ __launch_bounds__(256)
void qkv_mfma(const float* __restrict__ q_in, const float* __restrict__ k_in,
              const float* __restrict__ v_in,
              const float* __restrict__ Wq, const float* __restrict__ bq,
              const float* __restrict__ Wk, const float* __restrict__ bk,
              const float* __restrict__ Wv, const float* __restrict__ bv,
              unsigned short* __restrict__ Qo, unsigned short* __restrict__ Ko,
              unsigned short* __restrict__ Vo)
{
    const float *A, *W, *B; unsigned short* C;
    if (blockIdx.z == 0)      { A = q_in; W = Wq; B = bq; C = Qo; }
    else if (blockIdx.z == 1) { A = k_in; W = Wk; B = bk; C = Ko; }
    else                      { A = v_in; W = Wv; B = bv; C = Vo; }

    __shared__ __align__(16) short Alds[128*32];
    __shared__ __align__(16) short Blds[128*32];
    const int tid  = threadIdx.x;
    const int lane = tid & 63;
    const int wave = tid >> 6;
    const int lrow = lane & 15;
    const int lq   = lane >> 4;
    const int m0 = blockIdx.x * 128;
    const int n0 = blockIdx.y * 128;
    const int mw = (wave >> 1) * 64;
    const int nw = (wave & 1) * 64;
    const int K  = DMODEL;

    floatx4 zero = {0.f, 0.f, 0.f, 0.f};
    floatx4 acc[4][4];
    #pragma unroll
    for (int i = 0; i < 4; ++i)
        #pragma unroll
        for (int j = 0; j < 4; ++j) acc[i][j] = zero;

    for (int k0 = 0; k0 < K; k0 += 32) {
        #pragma unroll
        for (int rep = 0; rep < 2; ++rep) {
            int chunk = tid + rep * 256;
            int row = chunk >> 2;
            int col = (chunk & 3) << 3;
            *(uint4*)&Alds[row*32 + col] = cvt8(&A[(m0 + row) * K + k0 + col]);
            *(uint4*)&Blds[row*32 + col] = cvt8(&W[(n0 + row) * K + k0 + col]);
        }
        __syncthreads();
        short8 af[4], bfg[4];
        #pragma unroll
        for (int mi = 0; mi < 4; ++mi)
            af[mi] = *(const short8*)&Alds[(mw + mi*16 + lrow)*32 + lq*8];
        #pragma unroll
        for (int ni = 0; ni < 4; ++ni)
            bfg[ni] = *(const short8*)&Blds[(nw + ni*16 + lrow)*32 + lq*8];
        #pragma unroll
        for (int mi = 0; mi < 4; ++mi)
            #pragma unroll
            for (int ni = 0; ni < 4; ++ni)
                acc[mi][ni] = __builtin_amdgcn_mfma_f32_16x16x32_bf16(af[mi], bfg[ni], acc[mi][ni], 0, 0, 0);
        __syncthreads();
    }

    #pragma unroll
    for (int mi = 0; mi < 4; ++mi) {
        #pragma unroll
        for (int ni = 0; ni < 4; ++ni) {
            int n = n0 + nw + ni*16 + lrow;
            float bv_ = B[n];
            #pragma unroll
            for (int r = 0; r < 4; ++r) {
                int m = m0 + mw + mi*16 + lq*4 + r;
                C[m * DMODEL + n] = f2bf(acc[mi][ni][r] + bv_);
            }
        }
    }
}

__global__ __launch_bounds__(256)
void oproj_mfma(const unsigned short* __restrict__ Cx,
                const float* __restrict__ Wo, const float* __restrict__ bo,
                float* __restrict__ O32)
{
    __shared__ __align__(16) short Alds[128*32];
    __shared__ __align__(16) short Blds[128*32];
    const int tid  = threadIdx.x;
    const int lane = tid & 63;
    const int wave = tid >> 6;
    const int lrow = lane & 15;
    const int lq   = lane >> 4;
    const int m0 = blockIdx.x * 128;
    const int n0 = blockIdx.y * 128;
    const int mw = (wave >> 1) * 64;
    const int nw = (wave & 1) * 64;
    const int K  = DMODEL;

    floatx4 zero = {0.f, 0.f, 0.f, 0.f};
    floatx4 acc[4][4];
    #pragma unroll
    for (int i = 0; i < 4; ++i)
        #pragma unroll
        for (int j = 0; j < 4; ++j) acc[i][j] = zero;

    for (int k0 = 0; k0 < K; k0 += 32) {
        #pragma unroll
        for (int rep = 0; rep < 2; ++rep) {
            int chunk = tid + rep * 256;
            int row = chunk >> 2;
            int col = (chunk & 3) << 3;
            *(uint4*)&Alds[row*32 + col] = *(const uint4*)&Cx[(m0 + row) * K + k0 + col];
            *(uint4*)&Blds[row*32 + col] = cvt8(&Wo[(n0 + row) * K + k0 + col]);
        }
        __syncthreads();
        short8 af[4], bfg[4];
        #pragma unroll
        for (int mi = 0; mi < 4; ++mi)
            af[mi] = *(const short8*)&Alds[(mw + mi*16 + lrow)*32 + lq*8];
        #pragma unroll
        for (int ni = 0; ni < 4; ++ni)
            bfg[ni] = *(const short8*)&Blds[(nw + ni*16 + lrow)*32 + lq*8];
        #pragma unroll
        for (int mi = 0; mi < 4; ++mi)
            #pragma unroll
            for (int ni = 0; ni < 4; ++ni)
                acc[mi][ni] = __builtin_amdgcn_mfma_f32_16x16x32_bf16(af[mi], bfg[ni], acc[mi][ni], 0, 0, 0);
        __syncthreads();
    }

    #pragma unroll
    for (int mi = 0; mi < 4; ++mi) {
        #pragma unroll
        for (int ni = 0; ni < 4; ++ni) {
            int n = n0 + nw + ni*16 + lrow;
            float bv_ = bo[n];
            #pragma unroll
            for (int r = 0; r < 4; ++r) {
                int m = m0 + mw + mi*16 + lq*4 + r;
                O32[m * DMODEL + n] = acc[mi][ni][r] + bv_;
            }
        }
    }
}

// ---------------------------------------------------------------
// MFMA flash attention v3: S^T orientation + async staging.
//  - Q/K/VT staged with global_load_lds width=16 (lane-linear LDS).
//  - 16B-chunk XOR swizzle (cc ^ (row&7)) applied in GLOBAL addresses
//    so unpadded stride-64 LDS rows read conflict-lite as b128 frags.
//  - V pre-transposed globally (vt_kernel) - no per-iter transpose.
// NOTE: reference applies NO 1/sqrt(dh) scaling.
// ---------------------------------------------------------------
__global__ __launch_bounds__(256)
void attn_mfma3(const unsigned short* __restrict__ Q,
                const unsigned short* __restrict__ Kg,
                const unsigned short* __restrict__ VT,
                unsigned short* __restrict__ Ctx)
{
    __shared__ __align__(16) short Qs[64*64];
    __shared__ __align__(16) short Ks[64*64];
    __shared__ __align__(16) short Vt[64*64];
    __shared__ __align__(16) short Ps[4][16*72];

    const int tid  = threadIdx.x;
    const int lane = tid & 63;
    const int wave = tid >> 6;
    const int lrow = lane & 15;
    const int lq   = lane >> 4;

    const int q0 = blockIdx.x * 64;
    const int bh = blockIdx.y;
    const int off = (bh >> 4) * DMODEL + (bh & 15) * DH;
    const unsigned short* VTb = VT + bh * (DH * SEQ);

    // stage Q (async, swizzled)
    #pragma unroll
    for (int rep = 0; rep < 2; ++rep) {
        int c = rep*256 + wave*64 + lane;
        int r = c >> 3, cc = c & 7;
        const unsigned short* g = &Q[(q0 + r) * RS + off + ((cc ^ (r & 7)) << 3)];
        AS_LDS unsigned int* l = (AS_LDS unsigned int*)&Qs[(rep*256 + wave*64) * 8];
        __builtin_amdgcn_global_load_lds((const AS_GLOBAL unsigned int*)g, l, 16, 0, 0);
    }
    __syncthreads();

    short8 qf[2];
    #pragma unroll
    for (int ks = 0; ks < 2; ++ks) {
        int r = wave*16 + lrow;
        int cc = ks*4 + lq;
        qf[ks] = *(const short8*)&Qs[r*64 + ((cc ^ (r & 7)) << 3)];
    }

    floatx4 zero = {0.f, 0.f, 0.f, 0.f};
    float m_i = -1e30f, l_i = 0.f;
    floatx4 oacc[4];
    #pragma unroll
    for (int ni = 0; ni < 4; ++ni) oacc[ni] = zero;

    for (int kt = 0; kt < SEQ/64; ++kt) {
        __syncthreads();               // protect Ks/Vt from prior readers
        const int kbase = kt * 64;
        #pragma unroll
        for (int rep = 0; rep < 2; ++rep) {
            int c = rep*256 + wave*64 + lane;
            int r = c >> 3, cc = c & 7;
            int sw = ((cc ^ (r & 7)) << 3);
            const unsigned short* gk = &Kg[(kbase + r) * RS + off + sw];
            const unsigned short* gv = &VTb[r * SEQ + kbase + sw];
            AS_LDS unsigned int* lk = (AS_LDS unsigned int*)&Ks[(rep*256 + wave*64) * 8];
            AS_LDS unsigned int* lv = (AS_LDS unsigned int*)&Vt[(rep*256 + wave*64) * 8];
            __builtin_amdgcn_global_load_lds((const AS_GLOBAL unsigned int*)gk, lk, 16, 0, 0);
            __builtin_amdgcn_global_load_lds((const AS_GLOBAL unsigned int*)gv, lv, 16, 0, 0);
        }
        __syncthreads();               // drain vmcnt + visibility

        // ---- S^T = K Q^T : D[m=key][n=q] ----
        floatx4 sacc[4];
        #pragma unroll
        for (int ni = 0; ni < 4; ++ni) sacc[ni] = zero;
        #pragma unroll
        for (int ni = 0; ni < 4; ++ni) {
            #pragma unroll
            for (int ks = 0; ks < 2; ++ks) {
                int key = ni*16 + lrow;
                int cc  = ks*4 + lq;
                short8 kf = *(const short8*)&Ks[key*64 + ((cc ^ (key & 7)) << 3)];
                sacc[ni] = __builtin_amdgcn_mfma_f32_16x16x32_bf16(kf, qf[ks], sacc[ni], 0, 0, 0);
            }
        }

        // ---- online softmax (lane-local q) ----
        float mx = sacc[0][0];
        #pragma unroll
        for (int ni = 0; ni < 4; ++ni)
            #pragma unroll
            for (int r = 0; r < 4; ++r) mx = fmaxf(mx, sacc[ni][r]);
        mx = fmaxf(mx, __shfl_xor(mx, 16));
        mx = fmaxf(mx, __shfl_xor(mx, 32));
        float mnew = fmaxf(m_i, mx);
        float alpha = __expf(m_i - mnew);
        float p[4][4];
        float psum = 0.f;
        #pragma unroll
        for (int ni = 0; ni < 4; ++ni)
            #pragma unroll
            for (int r = 0; r < 4; ++r) {
                p[ni][r] = __expf(sacc[ni][r] - mnew);
                psum += p[ni][r];
            }
        psum += __shfl_xor(psum, 16);
        psum += __shfl_xor(psum, 32);
        l_i = l_i * alpha + psum;
        m_i = mnew;
        #pragma unroll
        for (int ni = 0; ni < 4; ++ni)
            #pragma unroll
            for (int r = 0; r < 4; ++r) oacc[ni][r] *= alpha;

        // ---- P: PsT[q=lrow][key], b64 writes ----
        #pragma unroll
        for (int ni = 0; ni < 4; ++ni) {
            uint2 pk;
            pk.x = (unsigned)f2bf(p[ni][0]) | ((unsigned)f2bf(p[ni][1]) << 16);
            pk.y = (unsigned)f2bf(p[ni][2]) | ((unsigned)f2bf(p[ni][3]) << 16);
            *(uint2*)&Ps[wave][lrow*72 + ni*16 + lq*4] = pk;
        }
        __builtin_amdgcn_wave_barrier();

        // ---- O^T += Vt P^T : D[m=d][n=q] ----
        short8 pf[2];
        #pragma unroll
        for (int ks = 0; ks < 2; ++ks)
            pf[ks] = *(const short8*)&Ps[wave][lrow*72 + ks*32 + lq*8];
        #pragma unroll
        for (int ni = 0; ni < 4; ++ni) {
            #pragma unroll
            for (int ks = 0; ks < 2; ++ks) {
                int d  = ni*16 + lrow;
                int cc = ks*4 + lq;
                short8 vf = *(const short8*)&Vt[d*64 + ((cc ^ (d & 7)) << 3)];
                oacc[ni] = __builtin_amdgcn_mfma_f32_16x16x32_bf16(vf, pf[ks], oacc[ni], 0, 0, 0);
            }
        }
    }

    const float inv = 1.f / l_i;
    const int q = q0 + wave*16 + lrow;
    #pragma unroll
    for (int ni = 0; ni < 4; ++ni) {
        uint2 ok;
        ok.x = (unsigned)f2bf(oacc[ni][0] * inv) | ((unsigned)f2bf(oacc[ni][1] * inv) << 16);
        ok.y = (unsigned)f2bf(oacc[ni][2] * inv) | ((unsigned)f2bf(oacc[ni][3] * inv) << 16);
        *(uint2*)&Ctx[q * RS + off + ni*16 + lq*4] = ok;
    }
}

// ---------------------------------------------------------------
// MFMA flash attention v2 (fallback path: V in normal layout).
// ---------------------------------------------------------------
__global__ __launch_bounds__(256)
void attn_mfma2(const unsigned short* __restrict__ Q,
                const unsigned short* __restrict__ Kg,
                const unsigned short* __restrict__ V,
                unsigned short* __restrict__ Ctx)
{
    __shared__ __align__(16) short Qs[64*72];
    __shared__ __align__(16) short Ks[64*72];
    __shared__ __align__(16) short Vt[64*72];
    __shared__ __align__(16) short Ps[4][16*72];

    const int tid  = threadIdx.x;
    const int lane = tid & 63;
    const int wave = tid >> 6;
    const int lrow = lane & 15;
    const int lq   = lane >> 4;

    const int q0 = blockIdx.x * 64;
    const int bh = blockIdx.y;
    const int off = (bh >> 4) * DMODEL + (bh & 15) * DH;

    #pragma unroll
    for (int rep = 0; rep < 2; ++rep) {
        int chunk = tid + rep * 256;
        int r = chunk >> 3;
        int c = (chunk & 7) << 3;
        *(uint4*)&Qs[r*72 + c] = *(const uint4*)&Q[(q0 + r) * RS + off + c];
    }
    __syncthreads();

    short8 qf[2];
    #pragma unroll
    for (int ks = 0; ks < 2; ++ks)
        qf[ks] = *(const short8*)&Qs[(wave*16 + lrow)*72 + ks*32 + lq*8];

    floatx4 zero = {0.f, 0.f, 0.f, 0.f};
    float m_i = -1e30f, l_i = 0.f;
    floatx4 oacc[4];
    #pragma unroll
    for (int ni = 0; ni < 4; ++ni) oacc[ni] = zero;

    for (int kt = 0; kt < SEQ/64; ++kt) {
        __syncthreads();
        const int kbase = kt * 64;
        #pragma unroll
        for (int rep = 0; rep < 2; ++rep) {
            int chunk = tid + rep * 256;
            int r = chunk >> 3;
            int c = (chunk & 7) << 3;
            *(uint4*)&Ks[r*72 + c] = *(const uint4*)&Kg[(kbase + r) * RS + off + c];
            uint4 vv = *(const uint4*)&V[(kbase + r) * RS + off + c];
            union { uint4 u; short s[8]; } uv; uv.u = vv;
            int swz = (chunk & 7) << 3;
            #pragma unroll
            for (int j = 0; j < 8; ++j)
                Vt[(c + j)*72 + (r ^ swz)] = uv.s[j];
        }
        __syncthreads();

        floatx4 sacc[4];
        #pragma unroll
        for (int ni = 0; ni < 4; ++ni) sacc[ni] = zero;
        #pragma unroll
        for (int ni = 0; ni < 4; ++ni) {
            #pragma unroll
            for (int ks = 0; ks < 2; ++ks) {
                short8 kf = *(const short8*)&Ks[(ni*16 + lrow)*72 + ks*32 + lq*8];
                sacc[ni] = __builtin_amdgcn_mfma_f32_16x16x32_bf16(kf, qf[ks], sacc[ni], 0, 0, 0);
            }
        }

        float mx = sacc[0][0];
        #pragma unroll
        for (int ni = 0; ni < 4; ++ni)
            #pragma unroll
            for (int r = 0; r < 4; ++r) mx = fmaxf(mx, sacc[ni][r]);
        mx = fmaxf(mx, __shfl_xor(mx, 16));
        mx = fmaxf(mx, __shfl_xor(mx, 32));
        float mnew = fmaxf(m_i, mx);
        float alpha = __expf(m_i - mnew);
        float p[4][4];
        float psum = 0.f;
        #pragma unroll
        for (int ni = 0; ni < 4; ++ni)
            #pragma unroll
            for (int r = 0; r < 4; ++r) {
                p[ni][r] = __expf(sacc[ni][r] - mnew);
                psum += p[ni][r];
            }
        psum += __shfl_xor(psum, 16);
        psum += __shfl_xor(psum, 32);
        l_i = l_i * alpha + psum;
        m_i = mnew;
        #pragma unroll
        for (int ni = 0; ni < 4; ++ni)
            #pragma unroll
            for (int r = 0; r < 4; ++r) oacc[ni][r] *= alpha;

        #pragma unroll
        for (int ni = 0; ni < 4; ++ni) {
            uint2 pk;
            pk.x = (unsigned)f2bf(p[ni][0]) | ((unsigned)f2bf(p[ni][1]) << 16);
            pk.y = (unsigned)f2bf(p[ni][2]) | ((unsigned)f2bf(p[ni][3]) << 16);
            *(uint2*)&Ps[wave][lrow*72 + ni*16 + lq*4] = pk;
        }
        __builtin_amdgcn_wave_barrier();

        short8 pf[2];
        #pragma unroll
        for (int ks = 0; ks < 2; ++ks)
            pf[ks] = *(const short8*)&Ps[wave][lrow*72 + ks*32 + lq*8];
        #pragma unroll
        for (int ni = 0; ni < 4; ++ni) {
            #pragma unroll
            for (int ks = 0; ks < 2; ++ks) {
                int d  = ni*16 + lrow;
                int kk = ks*32 + lq*8;
                int swz = ((d >> 3) & 7) << 3;
                short8 vf = *(const short8*)&Vt[d*72 + (kk ^ swz)];
                oacc[ni] = __builtin_amdgcn_mfma_f32_16x16x32_bf16(vf, pf[ks], oacc[ni], 0, 0, 0);
            }
        }
    }

    const float inv = 1.f / l_i;
    const int q = q0 + wave*16 + lrow;
    #pragma unroll
    for (int ni = 0; ni < 4; ++ni) {
        uint2 ok;
        ok.x = (unsigned)f2bf(oacc[ni][0] * inv) | ((unsigned)f2bf(oacc[ni][1] * inv) << 16);
        ok.y = (unsigned)f2bf(oacc[ni][2] * inv) | ((unsigned)f2bf(oacc[ni][3] * inv) << 16);
        *(uint2*)&Ctx[q * RS + off + ni*16 + lq*4] = ok;
    }
}

// ---------------------------------------------------------------
// LayerNorm(out + residual): fp32 in, fp32 out.
// ---------------------------------------------------------------
__global__ __launch_bounds__(256)
void ln2_kernel(const float* __restrict__ O,
                const float* __restrict__ resid,
                const float* __restrict__ w,
                const float* __restrict__ bb,
                float* __restrict__ out)
{
    __shared__ float r1[256];
    __shared__ float r2[256];
    const int row = blockIdx.x;
    const int tid = threadIdx.x;
    const int c4 = tid * 4;

    float4 o4 = *(const float4*)&O[row * DMODEL + c4];
    float4 q4 = *(const float4*)&resid[row * DMODEL + c4];
    float x0 = o4.x + q4.x;
    float x1 = o4.y + q4.y;
    float x2 = o4.z + q4.z;
    float x3 = o4.w + q4.w;

    r1[tid] = x0 + x1 + x2 + x3;
    r2[tid] = x0*x0 + x1*x1 + x2*x2 + x3*x3;
    __syncthreads();
    for (int st = 128; st > 0; st >>= 1) {
        if (tid < st) { r1[tid] += r1[tid + st]; r2[tid] += r2[tid + st]; }
        __syncthreads();
    }
    const float mean = r1[0] * (1.f / DMODEL);
    float var = r2[0] * (1.f / DMODEL) - mean * mean;
    var = fmaxf(var, 0.f);
    const float rstd = rsqrtf(var + LN_EPS);

    float4 w4 = *(const float4*)&w[c4];
    float4 b4 = *(const float4*)&bb[c4];
    float4 y;
    y.x = w4.x * ((x0 - mean) * rstd) + b4.x;
    y.y = w4.y * ((x1 - mean) * rstd) + b4.y;
    y.z = w4.z * ((x2 - mean) * rstd) + b4.z;
    y.w = w4.w * ((x3 - mean) * rstd) + b4.w;
    *(float4*)&out[row * DMODEL + c4] = y;
}

// ---------------------------------------------------------------
extern "C" void kernel_launch(void* const* d_in, const int* in_sizes, int n_in,
                              void* d_out, int out_size, void* d_ws, size_t ws_size,
                              hipStream_t stream) {
    const float* q_in = (const float*)d_in[0];
    const float* k_in = (const float*)d_in[1];
    const float* v_in = (const float*)d_in[2];
    const float* Wq = (const float*)d_in[3];  const float* bq = (const float*)d_in[4];
    const float* Wk = (const float*)d_in[5];  const float* bk = (const float*)d_in[6];
    const float* Wv = (const float*)d_in[7];  const float* bv = (const float*)d_in[8];
    const float* Wo = (const float*)d_in[9];  const float* bo = (const float*)d_in[10];
    const float* lnw = (const float*)d_in[11]; const float* lnb = (const float*)d_in[12];

    char* wsb = (char*)d_ws;
    unsigned short* QCtx = (unsigned short*)d_out;
    float*          outF = (float*)d_out;
    dim3 blk(256);

    if (ws_size >= (48u << 20)) {
        // ws: [0,24) qb,kb,vb | [24,32) W's | [32,40) Kb | [40,48) Vb
        // VT (8MB) overlays qb [0,8) (dead after qkv);
        // O32 (16MB) overlays [0,16) (VT dead after attn).
        unsigned short* qb  = (unsigned short*)(wsb);
        unsigned short* kb  = (unsigned short*)(wsb + (8u  << 20));
        unsigned short* vb  = (unsigned short*)(wsb + (16u << 20));
        unsigned short* Wqb = (unsigned short*)(wsb + (24u << 20));
        unsigned short* Wkb = (unsigned short*)(wsb + (26u << 20));
        unsigned short* Wvb = (unsigned short*)(wsb + (28u << 20));
        unsigned short* Wob = (unsigned short*)(wsb + (30u << 20));
        unsigned short* Kb  = (unsigned short*)(wsb + (32u << 20));
        unsigned short* Vb  = (unsigned short*)(wsb + (40u << 20));
        unsigned short* VT  = (unsigned short*)(wsb);
        float*          O32 = (float*)(wsb);

        cvt_kernel<<<dim3(512, 1, 7), blk, 0, stream>>>(
            q_in, k_in, v_in, Wq, Wk, Wv, Wo,
            qb, kb, vb, Wqb, Wkb, Wvb, Wob);
        qkv_bf16<<<dim3(MROWS/128, DMODEL/128, 3), blk, 0, stream>>>(
            qb, kb, vb, Wqb, bq, Wkb, bk, Wvb, bv, QCtx, Kb, Vb);
        vt_kernel<<<dim3(SEQ/64, BATCH*NHEAD), blk, 0, stream>>>(Vb, VT);
        attn_mfma3<<<dim3(SEQ/64, BATCH*NHEAD), blk, 0, stream>>>(QCtx, Kb, VT, QCtx);
        oproj_bf16<<<dim3(MROWS/128, DMODEL/128), blk, 0, stream>>>(QCtx, Wob, bo, O32);
        ln2_kernel<<<dim3(MROWS), blk, 0, stream>>>(O32, q_in, lnw, lnb, outF);
    } else if (ws_size >= (16u << 20)) {
        unsigned short* Kb  = (unsigned short*)(wsb);
        unsigned short* Vb  = (unsigned short*)(wsb + (8u << 20));
        float*          O32 = (float*)(wsb);
        qkv_mfma<<<dim3(MROWS/128, DMODEL/128, 3), blk, 0, stream>>>(
            q_in, k_in, v_in, Wq, bq, Wk, bk, Wv, bv, QCtx, Kb, Vb);
        attn_mfma2<<<dim3(SEQ/64, BATCH*NHEAD), blk, 0, stream>>>(QCtx, Kb, Vb, QCtx);
        oproj_mfma<<<dim3(MROWS/128, DMODEL/128), blk, 0, stream>>>(QCtx, Wo, bo, O32);
        ln2_kernel<<<dim3(MROWS), blk, 0, stream>>>(O32, q_in, lnw, lnb, outF);
    } else {
        beacon_kernel<<<1, 64, 0, stream>>>((float*)d_out, 300.0f);
    }
}